// Round 2
// baseline (3508.797 us; speedup 1.0000x reference)
//
#include <hip/hip_runtime.h>
#include <math.h>

#define H 128

typedef unsigned short u16;
typedef unsigned int u32;

__device__ __forceinline__ float bflo(u32 w) {           // low bf16 half -> f32
    union { u32 i; float f; } v; v.i = w << 16; return v.f;
}
__device__ __forceinline__ float bfhi(u32 w) {           // high bf16 half -> f32
    union { u32 i; float f; } v; v.i = w & 0xffff0000u; return v.f;
}
__device__ __forceinline__ u16 f2bf(float f) {           // f32 -> bf16 (RNE)
    union { float f; u32 i; } v; v.f = f;
    u32 r = v.i + 0x7fffu + ((v.i >> 16) & 1u);
    return (u16)(r >> 16);
}
__device__ __forceinline__ u32 pack2(float lo, float hi) {
    return (u32)f2bf(lo) | ((u32)f2bf(hi) << 16);
}
__device__ __forceinline__ float silu(float v) {
    return v / (1.0f + __expf(-v));
}

// Convert both 128x128 fp32 second-layer weight matrices to packed-bf16 in ws.
__global__ void cvt_kernel(const float* __restrict__ a, const float* __restrict__ b,
                           u32* __restrict__ outA, u32* __restrict__ outB) {
    int i = blockIdx.x * blockDim.x + threadIdx.x;   // i in [0, 8192)
    if (i < H * H / 2) {
        const float2 av = ((const float2*)a)[i];
        const float2 bv = ((const float2*)b)[i];
        outA[i] = pack2(av.x, av.y);
        outB[i] = pack2(bv.x, bv.y);
    }
}

// ---------------------------------------------------------------------------
// Edge kernel: message = silu( silu([x_s, x_r, dist] @ w1 + b1) @ w2 + b2 ),
// atomic-add into aggr[rec] (= d_out used as fp32 accumulator).
// One edge per wave; lane owns output columns j0=2*lane, j0+1.
// w1 rows 0..255 staged bf16-packed in 64KB LDS; row 256 (dist) in registers;
// w2 read as packed bf16 from ws (32KB -> L1-resident).
// ---------------------------------------------------------------------------
__global__ __launch_bounds__(256) void edge_kernel(
    const float* __restrict__ x, const float* __restrict__ pos,
    const int* __restrict__ ei,
    const float* __restrict__ w1, const float* __restrict__ b1,
    const u32* __restrict__ w2bf, const float* __restrict__ b2,
    float* __restrict__ aggr, int E)
{
    __shared__ u32 sw1[256 * 64];   // [row k][col-pair], 64 KiB
    const float2* w1f2 = (const float2*)w1;          // rows 0..255 = 16384 pairs
    for (int i = threadIdx.x; i < 256 * 64; i += 256) {
        const float2 w = w1f2[i];
        sw1[i] = pack2(w.x, w.y);
    }
    __syncthreads();

    const int lane = threadIdx.x & 63;
    const int wid  = threadIdx.x >> 6;
    const int wavesTotal = gridDim.x * 4;
    const int j0 = lane * 2;

    const float bb1_0 = b1[j0], bb1_1 = b1[j0 + 1];
    const float bb2_0 = b2[j0], bb2_1 = b2[j0 + 1];
    const float wd0   = w1[256 * H + j0];            // dist row, fp32
    const float wd1   = w1[256 * H + j0 + 1];

    for (int e = blockIdx.x * 4 + wid; e < E; e += wavesTotal) {
        const int s = ei[e];
        const int r = ei[E + e];
        const float dx = pos[s * 3 + 0] - pos[r * 3 + 0];
        const float dy = pos[s * 3 + 1] - pos[r * 3 + 1];
        const float dz = pos[s * 3 + 2] - pos[r * 3 + 2];
        const float dist = sqrtf(dx * dx + dy * dy + dz * dz);

        float a0 = bb1_0 + dist * wd0;
        float a1 = bb1_1 + dist * wd1;

        const float4* xs = (const float4*)(x + (size_t)s * H);
        const float4* xr = (const float4*)(x + (size_t)r * H);
        #pragma unroll 4
        for (int k4 = 0; k4 < 32; ++k4) {
            const float4 sv = xs[k4];                // wave-uniform
            const int base = k4 * 4 * 64 + lane;
            u32 w;
            w = sw1[base];           a0 += sv.x * bflo(w); a1 += sv.x * bfhi(w);
            w = sw1[base + 64];      a0 += sv.y * bflo(w); a1 += sv.y * bfhi(w);
            w = sw1[base + 128];     a0 += sv.z * bflo(w); a1 += sv.z * bfhi(w);
            w = sw1[base + 192];     a0 += sv.w * bflo(w); a1 += sv.w * bfhi(w);
        }
        #pragma unroll 4
        for (int k4 = 0; k4 < 32; ++k4) {
            const float4 sv = xr[k4];
            const int base = (128 + k4 * 4) * 64 + lane;
            u32 w;
            w = sw1[base];           a0 += sv.x * bflo(w); a1 += sv.x * bfhi(w);
            w = sw1[base + 64];      a0 += sv.y * bflo(w); a1 += sv.y * bfhi(w);
            w = sw1[base + 128];     a0 += sv.z * bflo(w); a1 += sv.z * bfhi(w);
            w = sw1[base + 192];     a0 += sv.w * bflo(w); a1 += sv.w * bfhi(w);
        }
        const float h0 = silu(a0), h1 = silu(a1);

        // layer 2: broadcast h across the wave via shuffles
        a0 = bb2_0; a1 = bb2_1;
        #pragma unroll 4
        for (int k2 = 0; k2 < 64; ++k2) {
            const float ha = __shfl(h0, k2);         // h[2*k2]
            const float hb = __shfl(h1, k2);         // h[2*k2+1]
            const u32 wa = w2bf[(2 * k2) * 64 + lane];
            const u32 wb = w2bf[(2 * k2 + 1) * 64 + lane];
            a0 += ha * bflo(wa) + hb * bflo(wb);
            a1 += ha * bfhi(wa) + hb * bfhi(wb);
        }
        atomicAdd(&aggr[(size_t)r * H + j0],     silu(a0));
        atomicAdd(&aggr[(size_t)r * H + j0 + 1], silu(a1));
    }
}

// ---------------------------------------------------------------------------
// Node kernel: update = silu([x, aggr] @ uw1 + ub1) @ uw2 + ub2  (no final SiLU)
// buf == d_out: holds aggr on entry (fp32), overwritten with the update.
// ---------------------------------------------------------------------------
__global__ __launch_bounds__(256) void node_kernel(
    const float* __restrict__ x, float* buf,
    const float* __restrict__ w1, const float* __restrict__ b1,
    const u32* __restrict__ w2bf, const float* __restrict__ b2, int N)
{
    __shared__ u32 sw1[256 * 64];   // full upd_w1 bf16-packed, 64 KiB
    const float2* w1f2 = (const float2*)w1;
    for (int i = threadIdx.x; i < 256 * 64; i += 256) {
        const float2 w = w1f2[i];
        sw1[i] = pack2(w.x, w.y);
    }
    __syncthreads();

    const int lane = threadIdx.x & 63;
    const int wid  = threadIdx.x >> 6;
    const int wavesTotal = gridDim.x * 4;
    const int j0 = lane * 2;

    const float bb1_0 = b1[j0], bb1_1 = b1[j0 + 1];
    const float bb2_0 = b2[j0], bb2_1 = b2[j0 + 1];

    for (int n = blockIdx.x * 4 + wid; n < N; n += wavesTotal) {
        float a0 = bb1_0, a1 = bb1_1;
        const float4* xn = (const float4*)(x   + (size_t)n * H);
        const float4* ag = (const float4*)(buf + (size_t)n * H);
        #pragma unroll 4
        for (int k4 = 0; k4 < 32; ++k4) {
            const float4 sv = xn[k4];
            const int base = k4 * 4 * 64 + lane;
            u32 w;
            w = sw1[base];           a0 += sv.x * bflo(w); a1 += sv.x * bfhi(w);
            w = sw1[base + 64];      a0 += sv.y * bflo(w); a1 += sv.y * bfhi(w);
            w = sw1[base + 128];     a0 += sv.z * bflo(w); a1 += sv.z * bfhi(w);
            w = sw1[base + 192];     a0 += sv.w * bflo(w); a1 += sv.w * bfhi(w);
        }
        #pragma unroll 4
        for (int k4 = 0; k4 < 32; ++k4) {
            const float4 sv = ag[k4];
            const int base = (128 + k4 * 4) * 64 + lane;
            u32 w;
            w = sw1[base];           a0 += sv.x * bflo(w); a1 += sv.x * bfhi(w);
            w = sw1[base + 64];      a0 += sv.y * bflo(w); a1 += sv.y * bfhi(w);
            w = sw1[base + 128];     a0 += sv.z * bflo(w); a1 += sv.z * bfhi(w);
            w = sw1[base + 192];     a0 += sv.w * bflo(w); a1 += sv.w * bfhi(w);
        }
        const float h0 = silu(a0), h1 = silu(a1);

        a0 = bb2_0; a1 = bb2_1;
        #pragma unroll 4
        for (int k2 = 0; k2 < 64; ++k2) {
            const float ha = __shfl(h0, k2);
            const float hb = __shfl(h1, k2);
            const u32 wa = w2bf[(2 * k2) * 64 + lane];
            const u32 wb = w2bf[(2 * k2 + 1) * 64 + lane];
            a0 += ha * bflo(wa) + hb * bflo(wb);
            a1 += ha * bfhi(wa) + hb * bfhi(wb);
        }
        buf[(size_t)n * H + j0]     = a0;   // final layer: no SiLU
        buf[(size_t)n * H + j0 + 1] = a1;
    }
}

extern "C" void kernel_launch(void* const* d_in, const int* in_sizes, int n_in,
                              void* d_out, int out_size, void* d_ws, size_t ws_size,
                              hipStream_t stream) {
    const float* x    = (const float*)d_in[0];
    const float* pos  = (const float*)d_in[1];
    const int*   ei   = (const int*)d_in[2];
    const float* mw1  = (const float*)d_in[3];
    const float* mb1  = (const float*)d_in[4];
    const float* mw2  = (const float*)d_in[5];
    const float* mb2  = (const float*)d_in[6];
    const float* uw1  = (const float*)d_in[7];
    const float* ub1  = (const float*)d_in[8];
    const float* uw2  = (const float*)d_in[9];
    const float* ub2  = (const float*)d_in[10];

    const int N = in_sizes[0] / H;
    const int E = in_sizes[2] / 2;

    u32* mw2bf = (u32*)d_ws;                 // 8192 u32 = 32 KiB
    u32* uw2bf = mw2bf + H * H / 2;          // 8192 u32 = 32 KiB

    cvt_kernel<<<(H * H / 2 + 255) / 256, 256, 0, stream>>>(mw2, uw2, mw2bf, uw2bf);

    float* buf = (float*)d_out;              // fp32 aggr accumulator, then output
    hipMemsetAsync(buf, 0, (size_t)N * H * sizeof(float), stream);

    edge_kernel<<<2048, 256, 0, stream>>>(x, pos, ei, mw1, mb1, mw2bf, mb2, buf, E);
    node_kernel<<<512,  256, 0, stream>>>(x, buf, uw1, ub1, uw2bf, ub2, N);
}

// Round 3
// 2465.731 us; speedup vs baseline: 1.4230x; 1.4230x over previous
//
#include <hip/hip_runtime.h>
#include <math.h>

#define H 128

typedef unsigned short u16;
typedef unsigned int u32;
typedef __attribute__((ext_vector_type(4))) u32 u32x4;
typedef __attribute__((ext_vector_type(8))) __bf16 bf16x8;
typedef __attribute__((ext_vector_type(16))) float f32x16;

union Frag { u32x4 u; bf16x8 b; };

__device__ __forceinline__ u16 bfr(float f) {            // f32 -> bf16 RNE
    union { float f; u32 i; } v; v.f = f;
    u32 r = v.i + 0x7fffu + ((v.i >> 16) & 1u);
    return (u16)(r >> 16);
}
__device__ __forceinline__ u32 pack2(float lo, float hi) {
    return (u32)bfr(lo) | ((u32)bfr(hi) << 16);
}
__device__ __forceinline__ float silu(float v) {
    float e = __expf(-v);
    return v * __builtin_amdgcn_rcpf(1.0f + e);
}
__device__ __forceinline__ bf16x8 f8frag(float4 lo, float4 hi) {
    Frag f;
    f.u = (u32x4){pack2(lo.x, lo.y), pack2(lo.z, lo.w),
                  pack2(hi.x, hi.y), pack2(hi.z, hi.w)};
    return f.b;
}
__device__ __forceinline__ f32x16 mfma(bf16x8 a, bf16x8 b, f32x16 c) {
    return __builtin_amdgcn_mfma_f32_32x32x16_bf16(a, b, c, 0, 0, 0);
}

// ---------------------------------------------------------------------------
// ws layout (u32 units):
//   mw1s @ 0      : 4ct x 17kb x 64lane x 4  (msg w1^T frags, kb16 = dist+b1 pad)
//   mw2s @ 17408  : 4ct x  9kb x 64lane x 4  (msg w2^T frags, kb8  = b2 pad)
//   uw1s @ 26624  : 4ct x 17kb x 64lane x 4  (upd w1^T frags, kb16 = b1 pad)
//   uw2s @ 44032  : 4ct x  9kb x 64lane x 4  (upd w2^T frags, kb8  = b2 pad)
// A-frag for slot (ct,kb,lane): 8 bf16 = W[k = kb*16 + (lane>>5)*8 + j][ct*32 + (lane&31)]
// ---------------------------------------------------------------------------
__global__ void prep_kernel(const float* __restrict__ mw1, const float* __restrict__ mb1,
                            const float* __restrict__ mw2, const float* __restrict__ mb2,
                            const float* __restrict__ uw1, const float* __restrict__ ub1,
                            const float* __restrict__ uw2, const float* __restrict__ ub2,
                            u32* __restrict__ ws) {
    int t = blockIdx.x * blockDim.x + threadIdx.x;
    if (t >= 13312) return;
    const float *W, *s0, *s1;
    int nK, slot, base;
    if (t < 4352)       { W = mw1; s0 = mw1 + 256 * H; s1 = mb1; nK = 256; slot = t;         base = 0;     }
    else if (t < 6656)  { W = mw2; s0 = mb2; s1 = nullptr;       nK = 128; slot = t - 4352;  base = 17408; }
    else if (t < 11008) { W = uw1; s0 = ub1; s1 = nullptr;       nK = 256; slot = t - 6656;  base = 26624; }
    else                { W = uw2; s0 = ub2; s1 = nullptr;       nK = 128; slot = t - 11008; base = 44032; }
    int lane = slot & 63, fb = slot >> 6;
    int ct, kb;
    if (nK == 256) { ct = fb / 17; kb = fb % 17; }
    else           { ct = fb / 9;  kb = fb % 9;  }
    int m = ct * 32 + (lane & 31);
    int q = lane >> 5;
    u32 out[4];
    #pragma unroll
    for (int p = 0; p < 4; ++p) {
        float v[2];
        #pragma unroll
        for (int h = 0; h < 2; ++h) {
            int k = kb * 16 + q * 8 + p * 2 + h;
            float val = 0.0f;
            if (k < nK)            val = W[(size_t)k * H + m];
            else if (k == nK)      val = s0 ? s0[m] : 0.0f;
            else if (k == nK + 1)  val = s1 ? s1[m] : 0.0f;
            v[h] = val;
        }
        out[p] = pack2(v[0], v[1]);
    }
    u32* dst = ws + base + (size_t)slot * 4;
    dst[0] = out[0]; dst[1] = out[1]; dst[2] = out[2]; dst[3] = out[3];
}

// ---------------------------------------------------------------------------
// Edge kernel: 64 edges per wave-iteration (2 subtiles of 32).
// D1[m=w1col][n=edge] = mfma(w1^T frag, state^T frag);  silu -> bf16 packed;
// layer2 B-frags built in-register via lane^32 shuffles; scatter fp32 atomics.
// ---------------------------------------------------------------------------
__global__ __launch_bounds__(256, 2) void edge_mfma(
    const float* __restrict__ x, const float* __restrict__ pos,
    const int* __restrict__ ei, const u32* __restrict__ ws,
    float* __restrict__ aggr, int E, int nIter)
{
    __shared__ u32 lds[16384];                         // 64 KiB: msg w1 frags kb<16
    {
        const u32x4* src = (const u32x4*)ws;           // mw1s base
        u32x4* dst = (u32x4*)lds;
        for (int i = threadIdx.x; i < 4096; i += 256) {
            int ln = i & 63, fb = i >> 6, ct = fb >> 4, kb = fb & 15;
            dst[i] = src[(ct * 17 + kb) * 64 + ln];
        }
    }
    __syncthreads();
    const u32* wsl1 = ws;                              // for kb16 pad frags
    const u32* wsl2 = ws + 17408;

    const int lane = threadIdx.x & 63;
    const int q = lane >> 5, el = lane & 31;
    const int gw  = blockIdx.x * 4 + (threadIdx.x >> 6);
    const int gws = gridDim.x * 4;

    for (int it = gw; it < nIter; it += gws) {
        const int e0 = it * 64;
        const int sA = ei[e0 + el],      rA = ei[E + e0 + el];
        const int sB = ei[e0 + 32 + el], rB = ei[E + e0 + 32 + el];
        float dA, dB;
        {
            float ax = pos[sA*3] - pos[rA*3], ay = pos[sA*3+1] - pos[rA*3+1], az = pos[sA*3+2] - pos[rA*3+2];
            dA = sqrtf(ax*ax + ay*ay + az*az);
            float bx = pos[sB*3] - pos[rB*3], by = pos[sB*3+1] - pos[rB*3+1], bz = pos[sB*3+2] - pos[rB*3+2];
            dB = sqrtf(bx*bx + by*by + bz*bz);
        }
        const float* xsA = x + (size_t)sA * H; const float* xrA = x + (size_t)rA * H;
        const float* xsB = x + (size_t)sB * H; const float* xrB = x + (size_t)rB * H;

        f32x16 acc[2][4];
        #pragma unroll
        for (int s = 0; s < 2; ++s)
            #pragma unroll
            for (int ct = 0; ct < 4; ++ct) acc[s][ct] = (f32x16)0.0f;

        // ---- layer 1: K = 256 real + pad ----
        #pragma unroll
        for (int kb = 0; kb < 16; ++kb) {
            const int f = kb * 16 + q * 8;
            const float* pA = (f < H) ? (xsA + f) : (xrA + f - H);
            const float* pB = (f < H) ? (xsB + f) : (xrB + f - H);
            bf16x8 bA = f8frag(*(const float4*)pA, *(const float4*)(pA + 4));
            bf16x8 bB = f8frag(*(const float4*)pB, *(const float4*)(pB + 4));
            #pragma unroll
            for (int ct = 0; ct < 4; ++ct) {
                Frag a; a.u = *(const u32x4*)&lds[((ct * 16 + kb) * 64 + lane) * 4];
                acc[0][ct] = mfma(a.b, bA, acc[0][ct]);
                acc[1][ct] = mfma(a.b, bB, acc[1][ct]);
            }
        }
        {   // pad kb=16: k=256 -> dist (row wd), k=257 -> 1.0 (row b1)
            Frag bA, bB;
            bA.u = (u32x4){0,0,0,0}; bB.u = (u32x4){0,0,0,0};
            if (q == 0) { bA.u.x = pack2(dA, 1.0f); bB.u.x = pack2(dB, 1.0f); }
            #pragma unroll
            for (int ct = 0; ct < 4; ++ct) {
                Frag a; a.u = *(const u32x4*)&wsl1[((size_t)(ct * 17 + 16) * 64 + lane) * 4];
                acc[0][ct] = mfma(a.b, bA.b, acc[0][ct]);
                acc[1][ct] = mfma(a.b, bB.b, acc[1][ct]);
            }
        }

        // ---- per subtile: silu -> pack -> layer 2 -> scatter ----
        #pragma unroll
        for (int s = 0; s < 2; ++s) {
            const int ridx = s ? rB : rA;
            u32 hp[4][4][2];   // [ct][grp][pair]: grp g = cols ct*32 + 8g + 4q + 0..3
            #pragma unroll
            for (int ct = 0; ct < 4; ++ct)
                #pragma unroll
                for (int g = 0; g < 4; ++g) {
                    float v0 = silu(acc[s][ct][4*g + 0]);
                    float v1 = silu(acc[s][ct][4*g + 1]);
                    float v2 = silu(acc[s][ct][4*g + 2]);
                    float v3 = silu(acc[s][ct][4*g + 3]);
                    hp[ct][g][0] = pack2(v0, v1);
                    hp[ct][g][1] = pack2(v2, v3);
                }

            f32x16 acc2[4];
            #pragma unroll
            for (int ct = 0; ct < 4; ++ct) acc2[ct] = (f32x16)0.0f;

            #pragma unroll
            for (int kb2 = 0; kb2 < 8; ++kb2) {
                const int om = 2 * kb2 + q;        // my octet (cols 8*om..+7)
                const int op = 2 * kb2 + 1 - q;    // partner's octet
                u32 sv0 = hp[op >> 2][op & 3][0];
                u32 sv1 = hp[op >> 2][op & 3][1];
                u32 r0 = (u32)__shfl((int)sv0, lane ^ 32);
                u32 r1 = (u32)__shfl((int)sv1, lane ^ 32);
                u32 w0 = hp[om >> 2][om & 3][0];
                u32 w1v = hp[om >> 2][om & 3][1];
                Frag bf;
                if (q == 0) bf.u = (u32x4){w0, w1v, r0, r1};
                else        bf.u = (u32x4){r0, r1, w0, w1v};
                #pragma unroll
                for (int ct2 = 0; ct2 < 4; ++ct2) {
                    Frag a; a.u = *(const u32x4*)&wsl2[((size_t)(ct2 * 9 + kb2) * 64 + lane) * 4];
                    acc2[ct2] = mfma(a.b, bf.b, acc2[ct2]);
                }
            }
            {   // pad kb2=8: k=128 -> 1.0 (row b2)
                Frag bf; bf.u = (u32x4){0,0,0,0};
                if (q == 0) bf.u.x = 0x00003F80u;  // bf16(1.0) in j=0
                #pragma unroll
                for (int ct2 = 0; ct2 < 4; ++ct2) {
                    Frag a; a.u = *(const u32x4*)&wsl2[((size_t)(ct2 * 9 + 8) * 64 + lane) * 4];
                    acc2[ct2] = mfma(a.b, bf.b, acc2[ct2]);
                }
            }
            // scatter: message = silu(acc2), col m = ct2*32 + (r&3) + 8*(r>>2) + 4q
            float* arow = aggr + (size_t)ridx * H;
            #pragma unroll
            for (int ct2 = 0; ct2 < 4; ++ct2)
                #pragma unroll
                for (int r = 0; r < 16; ++r) {
                    int m = ct2 * 32 + (r & 3) + 8 * (r >> 2) + 4 * q;
                    atomicAdd(arow + m, silu(acc2[ct2][r]));
                }
        }
    }
}

// ---------------------------------------------------------------------------
// Node kernel: same structure; inputs [x[n], aggr[n]] (no dist), plain stores.
// buf == d_out: aggr on entry, overwritten with final update (no SiLU at end).
// ---------------------------------------------------------------------------
__global__ __launch_bounds__(256, 2) void node_mfma(
    const float* __restrict__ x, float* __restrict__ buf,
    const u32* __restrict__ ws, int N, int nIter)
{
    __shared__ u32 lds[16384];
    const u32* wsl1 = ws + 26624;
    const u32* wsl2 = ws + 44032;
    {
        const u32x4* src = (const u32x4*)wsl1;
        u32x4* dst = (u32x4*)lds;
        for (int i = threadIdx.x; i < 4096; i += 256) {
            int ln = i & 63, fb = i >> 6, ct = fb >> 4, kb = fb & 15;
            dst[i] = src[(ct * 17 + kb) * 64 + ln];
        }
    }
    __syncthreads();

    const int lane = threadIdx.x & 63;
    const int q = lane >> 5, el = lane & 31;
    const int gw  = blockIdx.x * 4 + (threadIdx.x >> 6);
    const int gws = gridDim.x * 4;

    for (int it = gw; it < nIter; it += gws) {
        const int n0 = it * 64;
        const int nA = n0 + el, nB = n0 + 32 + el;
        const int ncA = (nA < N) ? nA : (N - 1);
        const int ncB = (nB < N) ? nB : (N - 1);
        const float* xA = x + (size_t)ncA * H;  const float* gA = buf + (size_t)ncA * H;
        const float* xB = x + (size_t)ncB * H;  const float* gB = buf + (size_t)ncB * H;

        f32x16 acc[2][4];
        #pragma unroll
        for (int s = 0; s < 2; ++s)
            #pragma unroll
            for (int ct = 0; ct < 4; ++ct) acc[s][ct] = (f32x16)0.0f;

        #pragma unroll
        for (int kb = 0; kb < 16; ++kb) {
            const int f = kb * 16 + q * 8;
            const float* pA = (f < H) ? (xA + f) : (gA + f - H);
            const float* pB = (f < H) ? (xB + f) : (gB + f - H);
            bf16x8 bA = f8frag(*(const float4*)pA, *(const float4*)(pA + 4));
            bf16x8 bB = f8frag(*(const float4*)pB, *(const float4*)(pB + 4));
            #pragma unroll
            for (int ct = 0; ct < 4; ++ct) {
                Frag a; a.u = *(const u32x4*)&lds[((ct * 16 + kb) * 64 + lane) * 4];
                acc[0][ct] = mfma(a.b, bA, acc[0][ct]);
                acc[1][ct] = mfma(a.b, bB, acc[1][ct]);
            }
        }
        {   // pad kb=16: k=256 -> 1.0 (row ub1)
            Frag bp; bp.u = (u32x4){0,0,0,0};
            if (q == 0) bp.u.x = 0x00003F80u;
            #pragma unroll
            for (int ct = 0; ct < 4; ++ct) {
                Frag a; a.u = *(const u32x4*)&wsl1[((size_t)(ct * 17 + 16) * 64 + lane) * 4];
                acc[0][ct] = mfma(a.b, bp.b, acc[0][ct]);
                acc[1][ct] = mfma(a.b, bp.b, acc[1][ct]);
            }
        }

        #pragma unroll
        for (int s = 0; s < 2; ++s) {
            const int nn = s ? nB : nA;
            u32 hp[4][4][2];
            #pragma unroll
            for (int ct = 0; ct < 4; ++ct)
                #pragma unroll
                for (int g = 0; g < 4; ++g) {
                    float v0 = silu(acc[s][ct][4*g + 0]);
                    float v1 = silu(acc[s][ct][4*g + 1]);
                    float v2 = silu(acc[s][ct][4*g + 2]);
                    float v3 = silu(acc[s][ct][4*g + 3]);
                    hp[ct][g][0] = pack2(v0, v1);
                    hp[ct][g][1] = pack2(v2, v3);
                }

            f32x16 acc2[4];
            #pragma unroll
            for (int ct = 0; ct < 4; ++ct) acc2[ct] = (f32x16)0.0f;

            #pragma unroll
            for (int kb2 = 0; kb2 < 8; ++kb2) {
                const int om = 2 * kb2 + q;
                const int op = 2 * kb2 + 1 - q;
                u32 sv0 = hp[op >> 2][op & 3][0];
                u32 sv1 = hp[op >> 2][op & 3][1];
                u32 r0 = (u32)__shfl((int)sv0, lane ^ 32);
                u32 r1 = (u32)__shfl((int)sv1, lane ^ 32);
                u32 w0 = hp[om >> 2][om & 3][0];
                u32 w1v = hp[om >> 2][om & 3][1];
                Frag bf;
                if (q == 0) bf.u = (u32x4){w0, w1v, r0, r1};
                else        bf.u = (u32x4){r0, r1, w0, w1v};
                #pragma unroll
                for (int ct2 = 0; ct2 < 4; ++ct2) {
                    Frag a; a.u = *(const u32x4*)&wsl2[((size_t)(ct2 * 9 + kb2) * 64 + lane) * 4];
                    acc2[ct2] = mfma(a.b, bf.b, acc2[ct2]);
                }
            }
            {
                Frag bf; bf.u = (u32x4){0,0,0,0};
                if (q == 0) bf.u.x = 0x00003F80u;
                #pragma unroll
                for (int ct2 = 0; ct2 < 4; ++ct2) {
                    Frag a; a.u = *(const u32x4*)&wsl2[((size_t)(ct2 * 9 + 8) * 64 + lane) * 4];
                    acc2[ct2] = mfma(a.b, bf.b, acc2[ct2]);
                }
            }
            if (nn < N) {
                float* orow = buf + (size_t)nn * H;
                #pragma unroll
                for (int ct2 = 0; ct2 < 4; ++ct2)
                    #pragma unroll
                    for (int g = 0; g < 4; ++g) {
                        float4 v = { acc2[ct2][4*g + 0], acc2[ct2][4*g + 1],
                                     acc2[ct2][4*g + 2], acc2[ct2][4*g + 3] };
                        *(float4*)(orow + ct2 * 32 + 8 * g + 4 * q) = v;  // no final SiLU
                    }
            }
        }
    }
}

extern "C" void kernel_launch(void* const* d_in, const int* in_sizes, int n_in,
                              void* d_out, int out_size, void* d_ws, size_t ws_size,
                              hipStream_t stream) {
    const float* x    = (const float*)d_in[0];
    const float* pos  = (const float*)d_in[1];
    const int*   ei   = (const int*)d_in[2];
    const float* mw1  = (const float*)d_in[3];
    const float* mb1  = (const float*)d_in[4];
    const float* mw2  = (const float*)d_in[5];
    const float* mb2  = (const float*)d_in[6];
    const float* uw1  = (const float*)d_in[7];
    const float* ub1  = (const float*)d_in[8];
    const float* uw2  = (const float*)d_in[9];
    const float* ub2  = (const float*)d_in[10];

    const int N = in_sizes[0] / H;
    const int E = in_sizes[2] / 2;

    u32* ws = (u32*)d_ws;                         // 212992 B of swizzled weight frags
    prep_kernel<<<52, 256, 0, stream>>>(mw1, mb1, mw2, mb2, uw1, ub1, uw2, ub2, ws);

    float* buf = (float*)d_out;                   // fp32 aggr accumulator, then output
    hipMemsetAsync(buf, 0, (size_t)N * H * sizeof(float), stream);

    const int nIterE = E / 64;                    // E = 640000 -> 10000
    const int nIterN = (N + 63) / 64;
    edge_mfma<<<512, 256, 0, stream>>>(x, pos, ei, ws, buf, E, nIterE);
    node_mfma<<<256, 256, 0, stream>>>(x, buf, ws, N, nIterN);
}

// Round 4
// 1982.881 us; speedup vs baseline: 1.7695x; 1.2435x over previous
//
#include <hip/hip_runtime.h>
#include <math.h>

#define H 128

typedef unsigned short u16;
typedef unsigned int u32;
typedef __attribute__((ext_vector_type(4))) u32 u32x4;
typedef __attribute__((ext_vector_type(8))) __bf16 bf16x8;
typedef __attribute__((ext_vector_type(16))) float f32x16;

union Frag { u32x4 u; bf16x8 b; };

__device__ __forceinline__ u16 bfr(float f) {            // f32 -> bf16 RNE
    union { float f; u32 i; } v; v.f = f;
    u32 r = v.i + 0x7fffu + ((v.i >> 16) & 1u);
    return (u16)(r >> 16);
}
__device__ __forceinline__ u32 pack2(float lo, float hi) {
    return (u32)bfr(lo) | ((u32)bfr(hi) << 16);
}
__device__ __forceinline__ float silu(float v) {
    float e = __expf(-v);
    return v * __builtin_amdgcn_rcpf(1.0f + e);
}
__device__ __forceinline__ bf16x8 f8frag(float4 lo, float4 hi) {
    Frag f;
    f.u = (u32x4){pack2(lo.x, lo.y), pack2(lo.z, lo.w),
                  pack2(hi.x, hi.y), pack2(hi.z, hi.w)};
    return f.b;
}
__device__ __forceinline__ f32x16 mfma(bf16x8 a, bf16x8 b, f32x16 c) {
    return __builtin_amdgcn_mfma_f32_32x32x16_bf16(a, b, c, 0, 0, 0);
}

// ---------------------------------------------------------------------------
// ws frag region (u32 units):
//   mw1s @ 0      : 4ct x 17kb x 64lane x 4   (msg w1^T frags; kb16 = dist+b1 pad)
//   mw2s @ 17408  : 4ct x  9kb x 64lane x 4   (msg w2^T frags; kb8  = b2 pad)
//   uw1s @ 26624  : 4ct x 17kb x 64lane x 4   (upd w1^T frags; kb16 = b1 pad)
//   uw2s @ 44032  : 4ct x  9kb x 64lane x 4   (upd w2^T frags; kb8  = b2 pad)
// A-frag (ct,kb,lane): 8 bf16 = W[k = kb*16 + (lane>>5)*8 + j][ct*32 + (lane&31)]
// ---------------------------------------------------------------------------
__global__ void prep_kernel(const float* __restrict__ mw1, const float* __restrict__ mb1,
                            const float* __restrict__ mw2, const float* __restrict__ mb2,
                            const float* __restrict__ uw1, const float* __restrict__ ub1,
                            const float* __restrict__ uw2, const float* __restrict__ ub2,
                            u32* __restrict__ ws) {
    int t = blockIdx.x * blockDim.x + threadIdx.x;
    if (t >= 13312) return;
    const float *W, *s0, *s1;
    int nK, slot, base;
    if (t < 4352)       { W = mw1; s0 = mw1 + 256 * H; s1 = mb1; nK = 256; slot = t;         base = 0;     }
    else if (t < 6656)  { W = mw2; s0 = mb2; s1 = nullptr;       nK = 128; slot = t - 4352;  base = 17408; }
    else if (t < 11008) { W = uw1; s0 = ub1; s1 = nullptr;       nK = 256; slot = t - 6656;  base = 26624; }
    else                { W = uw2; s0 = ub2; s1 = nullptr;       nK = 128; slot = t - 11008; base = 44032; }
    int lane = slot & 63, fb = slot >> 6;
    int ct, kb;
    if (nK == 256) { ct = fb / 17; kb = fb % 17; }
    else           { ct = fb / 9;  kb = fb % 9;  }
    int m = ct * 32 + (lane & 31);
    int q = lane >> 5;
    u32 out[4];
    #pragma unroll
    for (int p = 0; p < 4; ++p) {
        float v[2];
        #pragma unroll
        for (int h = 0; h < 2; ++h) {
            int k = kb * 16 + q * 8 + p * 2 + h;
            float val = 0.0f;
            if (k < nK)            val = W[(size_t)k * H + m];
            else if (k == nK)      val = s0 ? s0[m] : 0.0f;
            else if (k == nK + 1)  val = s1 ? s1[m] : 0.0f;
            v[h] = val;
        }
        out[p] = pack2(v[0], v[1]);
    }
    u32* dst = ws + base + (size_t)slot * 4;
    dst[0] = out[0]; dst[1] = out[1]; dst[2] = out[2]; dst[3] = out[3];
}

// ---------------------------------------------------------------------------
// pq_gemm: out[n] = x[n] @ W1[kbBase*16 : kbBase*16+128]  (+ b1 if withBias)
// 64 nodes per wave-iter (2 subtiles).  A-frags read straight from ws (L1/L2).
// ---------------------------------------------------------------------------
__global__ __launch_bounds__(256, 2) void pq_gemm(
    const float* __restrict__ x, const u32* __restrict__ mw1s,
    float* __restrict__ out, int kbBase, int withBias, int N, int nIter)
{
    const int lane = threadIdx.x & 63;
    const int q = lane >> 5, el = lane & 31;
    const int gw  = blockIdx.x * 4 + (threadIdx.x >> 6);
    const int gws = gridDim.x * 4;

    for (int it = gw; it < nIter; it += gws) {
        const int n0 = it * 64;
        const int nA = n0 + el, nB = n0 + 32 + el;
        const int ncA = (nA < N) ? nA : (N - 1);
        const int ncB = (nB < N) ? nB : (N - 1);
        const float* xA = x + (size_t)ncA * H;
        const float* xB = x + (size_t)ncB * H;

        f32x16 acc[2][4];
        #pragma unroll
        for (int s = 0; s < 2; ++s)
            #pragma unroll
            for (int ct = 0; ct < 4; ++ct) acc[s][ct] = (f32x16)0.0f;

        #pragma unroll
        for (int kb = 0; kb < 8; ++kb) {
            const int f = kb * 16 + q * 8;
            bf16x8 bA = f8frag(*(const float4*)(xA + f), *(const float4*)(xA + f + 4));
            bf16x8 bB = f8frag(*(const float4*)(xB + f), *(const float4*)(xB + f + 4));
            #pragma unroll
            for (int ct = 0; ct < 4; ++ct) {
                Frag a; a.u = *(const u32x4*)&mw1s[((size_t)(ct * 17 + kbBase + kb) * 64 + lane) * 4];
                acc[0][ct] = mfma(a.b, bA, acc[0][ct]);
                acc[1][ct] = mfma(a.b, bB, acc[1][ct]);
            }
        }
        if (withBias) {   // pad kb16: k=256 -> 0 (skip dist row), k=257 -> 1.0 (b1)
            Frag bp; bp.u = (u32x4){0, 0, 0, 0};
            if (q == 0) bp.u.x = pack2(0.0f, 1.0f);
            #pragma unroll
            for (int ct = 0; ct < 4; ++ct) {
                Frag a; a.u = *(const u32x4*)&mw1s[((size_t)(ct * 17 + 16) * 64 + lane) * 4];
                acc[0][ct] = mfma(a.b, bp.b, acc[0][ct]);
                acc[1][ct] = mfma(a.b, bp.b, acc[1][ct]);
            }
        }
        #pragma unroll
        for (int s = 0; s < 2; ++s) {
            const int nn = s ? nB : nA;
            if (nn < N) {
                float* orow = out + (size_t)nn * H;
                #pragma unroll
                for (int ct = 0; ct < 4; ++ct)
                    #pragma unroll
                    for (int g = 0; g < 4; ++g) {
                        float4 v = { acc[s][ct][4*g + 0], acc[s][ct][4*g + 1],
                                     acc[s][ct][4*g + 2], acc[s][ct][4*g + 3] };
                        *(float4*)(orow + ct * 32 + 8 * g + 4 * q) = v;
                    }
            }
        }
    }
}

// ---------------------------------------------------------------------------
// bucket_fill: per edge, slot = atomicAdd(deg[rec]); bucket[rec*64+slot] = (send, dist)
// ---------------------------------------------------------------------------
__global__ void bucket_fill(const float* __restrict__ pos, const int* __restrict__ ei,
                            int* __restrict__ deg, int2* __restrict__ bucket, int E)
{
    int e = blockIdx.x * blockDim.x + threadIdx.x;
    if (e >= E) return;
    const int s = ei[e];
    const int r = ei[E + e];
    const float dx = pos[s*3]   - pos[r*3];
    const float dy = pos[s*3+1] - pos[r*3+1];
    const float dz = pos[s*3+2] - pos[r*3+2];
    const float dist = sqrtf(dx*dx + dy*dy + dz*dz);
    int slot = atomicAdd(&deg[r], 1);
    if (slot < 64) bucket[(size_t)r * 64 + slot] = make_int2(s, __float_as_int(dist));
}

// ---------------------------------------------------------------------------
// aggregate: one wave per node n.
//   h_e = silu(P[send_e] + Q[n] + dist_e * wd)           (elementwise, fp32)
//   msg_e = silu(h_e @ w2 + b2)                          (MFMA, b2 via pad row)
//   out[n] = sum_e msg_e                                 (shfl_xor over edge lanes)
// Pad lanes (el >= deg) get zero B-frags -> contribute exactly 0. No atomics.
// ---------------------------------------------------------------------------
__global__ __launch_bounds__(256, 4) void aggregate_kernel(
    const float* __restrict__ P, const float* __restrict__ Q,
    const float* __restrict__ wd, const u32* __restrict__ wsl2,
    const int* __restrict__ deg, const int2* __restrict__ bucket,
    float* __restrict__ out, int N)
{
    __shared__ u32x4 l2f[2304];                       // msg w2^T frags, 36 KiB
    for (int i = threadIdx.x; i < 2304; i += 256) l2f[i] = ((const u32x4*)wsl2)[i];
    __syncthreads();

    const int lane = threadIdx.x & 63;
    const int q = lane >> 5, el = lane & 31;
    const int gw  = blockIdx.x * 4 + (threadIdx.x >> 6);
    const int gws = gridDim.x * 4;

    for (int n = gw; n < N; n += gws) {
        int dn = deg[n]; dn = (dn > 64) ? 64 : dn;
        const int nt = (dn + 31) >> 5;
        const float* Qn = Q + (size_t)n * H;

        f32x16 acc2[4];
        #pragma unroll
        for (int ct2 = 0; ct2 < 4; ++ct2) acc2[ct2] = (f32x16)0.0f;

        for (int t = 0; t < nt; ++t) {
            const int eIdx = t * 32 + el;
            const bool valid = eIdx < dn;
            int2 rec = valid ? bucket[(size_t)n * 64 + eIdx] : make_int2(0, 0);
            const float* Prow = P + (size_t)rec.x * H;
            const float dist = __int_as_float(rec.y);

            #pragma unroll
            for (int kb2 = 0; kb2 < 8; ++kb2) {
                const int f = kb2 * 16 + q * 8;
                const float4 p0 = *(const float4*)(Prow + f);
                const float4 p1 = *(const float4*)(Prow + f + 4);
                const float4 q0 = *(const float4*)(Qn + f);
                const float4 q1 = *(const float4*)(Qn + f + 4);
                const float4 w0 = *(const float4*)(wd + f);
                const float4 w1 = *(const float4*)(wd + f + 4);
                const float v0 = silu(p0.x + q0.x + dist * w0.x);
                const float v1 = silu(p0.y + q0.y + dist * w0.y);
                const float v2 = silu(p0.z + q0.z + dist * w0.z);
                const float v3 = silu(p0.w + q0.w + dist * w0.w);
                const float v4 = silu(p1.x + q1.x + dist * w1.x);
                const float v5 = silu(p1.y + q1.y + dist * w1.y);
                const float v6 = silu(p1.z + q1.z + dist * w1.z);
                const float v7 = silu(p1.w + q1.w + dist * w1.w);
                Frag bf;
                bf.u = (u32x4){pack2(v0, v1), pack2(v2, v3), pack2(v4, v5), pack2(v6, v7)};
                if (!valid) bf.u = (u32x4){0, 0, 0, 0};
                #pragma unroll
                for (int ct2 = 0; ct2 < 4; ++ct2) {
                    Frag a; a.u = l2f[(ct2 * 9 + kb2) * 64 + lane];
                    acc2[ct2] = mfma(a.b, bf.b, acc2[ct2]);
                }
            }
            {   // pad kb2=8: k=128 -> 1.0 (b2 row), valid edges only
                Frag bf; bf.u = (u32x4){0, 0, 0, 0};
                if (valid && q == 0) bf.u.x = 0x00003F80u;
                #pragma unroll
                for (int ct2 = 0; ct2 < 4; ++ct2) {
                    Frag a; a.u = l2f[(ct2 * 9 + 8) * 64 + lane];
                    acc2[ct2] = mfma(a.b, bf.b, acc2[ct2]);
                }
            }
        }

        // silu -> sum over the 32 edge lanes -> single plain store per col
        float* orow = out + (size_t)n * H;
        #pragma unroll
        for (int ct2 = 0; ct2 < 4; ++ct2)
            #pragma unroll
            for (int r = 0; r < 16; ++r) {
                float m = silu(acc2[ct2][r]);
                m += __shfl_xor(m, 1);
                m += __shfl_xor(m, 2);
                m += __shfl_xor(m, 4);
                m += __shfl_xor(m, 8);
                m += __shfl_xor(m, 16);
                if (el == 0) orow[ct2 * 32 + (r & 3) + 8 * (r >> 2) + 4 * q] = m;
            }
    }
}

// ---------------------------------------------------------------------------
// FALLBACK (ws too small): round-3 edge kernel with fp32 atomics.
// ---------------------------------------------------------------------------
__global__ __launch_bounds__(256, 2) void edge_mfma(
    const float* __restrict__ x, const float* __restrict__ pos,
    const int* __restrict__ ei, const u32* __restrict__ ws,
    float* __restrict__ aggr, int E, int nIter)
{
    __shared__ u32 lds[16384];
    {
        const u32x4* src = (const u32x4*)ws;
        u32x4* dst = (u32x4*)lds;
        for (int i = threadIdx.x; i < 4096; i += 256) {
            int ln = i & 63, fb = i >> 6, ct = fb >> 4, kb = fb & 15;
            dst[i] = src[(ct * 17 + kb) * 64 + ln];
        }
    }
    __syncthreads();
    const u32* wsl1 = ws;
    const u32* wsl2 = ws + 17408;

    const int lane = threadIdx.x & 63;
    const int q = lane >> 5, el = lane & 31;
    const int gw  = blockIdx.x * 4 + (threadIdx.x >> 6);
    const int gws = gridDim.x * 4;

    for (int it = gw; it < nIter; it += gws) {
        const int e0 = it * 64;
        const int sA = ei[e0 + el],      rA = ei[E + e0 + el];
        const int sB = ei[e0 + 32 + el], rB = ei[E + e0 + 32 + el];
        float dA, dB;
        {
            float ax = pos[sA*3] - pos[rA*3], ay = pos[sA*3+1] - pos[rA*3+1], az = pos[sA*3+2] - pos[rA*3+2];
            dA = sqrtf(ax*ax + ay*ay + az*az);
            float bx = pos[sB*3] - pos[rB*3], by = pos[sB*3+1] - pos[rB*3+1], bz = pos[sB*3+2] - pos[rB*3+2];
            dB = sqrtf(bx*bx + by*by + bz*bz);
        }
        const float* xsA = x + (size_t)sA * H; const float* xrA = x + (size_t)rA * H;
        const float* xsB = x + (size_t)sB * H; const float* xrB = x + (size_t)rB * H;

        f32x16 acc[2][4];
        #pragma unroll
        for (int s = 0; s < 2; ++s)
            #pragma unroll
            for (int ct = 0; ct < 4; ++ct) acc[s][ct] = (f32x16)0.0f;

        #pragma unroll
        for (int kb = 0; kb < 16; ++kb) {
            const int f = kb * 16 + q * 8;
            const float* pA = (f < H) ? (xsA + f) : (xrA + f - H);
            const float* pB = (f < H) ? (xsB + f) : (xrB + f - H);
            bf16x8 bA = f8frag(*(const float4*)pA, *(const float4*)(pA + 4));
            bf16x8 bB = f8frag(*(const float4*)pB, *(const float4*)(pB + 4));
            #pragma unroll
            for (int ct = 0; ct < 4; ++ct) {
                Frag a; a.u = *(const u32x4*)&lds[((ct * 16 + kb) * 64 + lane) * 4];
                acc[0][ct] = mfma(a.b, bA, acc[0][ct]);
                acc[1][ct] = mfma(a.b, bB, acc[1][ct]);
            }
        }
        {
            Frag bA, bB;
            bA.u = (u32x4){0,0,0,0}; bB.u = (u32x4){0,0,0,0};
            if (q == 0) { bA.u.x = pack2(dA, 1.0f); bB.u.x = pack2(dB, 1.0f); }
            #pragma unroll
            for (int ct = 0; ct < 4; ++ct) {
                Frag a; a.u = *(const u32x4*)&wsl1[((size_t)(ct * 17 + 16) * 64 + lane) * 4];
                acc[0][ct] = mfma(a.b, bA.b, acc[0][ct]);
                acc[1][ct] = mfma(a.b, bB.b, acc[1][ct]);
            }
        }

        #pragma unroll
        for (int s = 0; s < 2; ++s) {
            const int ridx = s ? rB : rA;
            u32 hp[4][4][2];
            #pragma unroll
            for (int ct = 0; ct < 4; ++ct)
                #pragma unroll
                for (int g = 0; g < 4; ++g) {
                    float v0 = silu(acc[s][ct][4*g + 0]);
                    float v1 = silu(acc[s][ct][4*g + 1]);
                    float v2 = silu(acc[s][ct][4*g + 2]);
                    float v3 = silu(acc[s][ct][4*g + 3]);
                    hp[ct][g][0] = pack2(v0, v1);
                    hp[ct][g][1] = pack2(v2, v3);
                }

            f32x16 acc2[4];
            #pragma unroll
            for (int ct = 0; ct < 4; ++ct) acc2[ct] = (f32x16)0.0f;

            #pragma unroll
            for (int kb2 = 0; kb2 < 8; ++kb2) {
                const int om = 2 * kb2 + q;
                const int op = 2 * kb2 + 1 - q;
                u32 sv0 = hp[op >> 2][op & 3][0];
                u32 sv1 = hp[op >> 2][op & 3][1];
                u32 r0 = (u32)__shfl((int)sv0, lane ^ 32);
                u32 r1 = (u32)__shfl((int)sv1, lane ^ 32);
                u32 w0 = hp[om >> 2][om & 3][0];
                u32 w1v = hp[om >> 2][om & 3][1];
                Frag bf;
                if (q == 0) bf.u = (u32x4){w0, w1v, r0, r1};
                else        bf.u = (u32x4){r0, r1, w0, w1v};
                #pragma unroll
                for (int ct2 = 0; ct2 < 4; ++ct2) {
                    Frag a; a.u = *(const u32x4*)&wsl2[((size_t)(ct2 * 9 + kb2) * 64 + lane) * 4];
                    acc2[ct2] = mfma(a.b, bf.b, acc2[ct2]);
                }
            }
            {
                Frag bf; bf.u = (u32x4){0,0,0,0};
                if (q == 0) bf.u.x = 0x00003F80u;
                #pragma unroll
                for (int ct2 = 0; ct2 < 4; ++ct2) {
                    Frag a; a.u = *(const u32x4*)&wsl2[((size_t)(ct2 * 9 + 8) * 64 + lane) * 4];
                    acc2[ct2] = mfma(a.b, bf.b, acc2[ct2]);
                }
            }
            float* arow = aggr + (size_t)ridx * H;
            #pragma unroll
            for (int ct2 = 0; ct2 < 4; ++ct2)
                #pragma unroll
                for (int r = 0; r < 16; ++r) {
                    int m = ct2 * 32 + (r & 3) + 8 * (r >> 2) + 4 * q;
                    atomicAdd(arow + m, silu(acc2[ct2][r]));
                }
        }
    }
}

// ---------------------------------------------------------------------------
// Node update MLP: update = silu([x, aggr] @ uw1 + ub1) @ uw2 + ub2
// buf == d_out: aggr rows on entry, overwritten with the final update.
// ---------------------------------------------------------------------------
__global__ __launch_bounds__(256, 2) void node_mfma(
    const float* __restrict__ x, float* __restrict__ buf,
    const u32* __restrict__ ws, int N, int nIter)
{
    __shared__ u32 lds[16384];
    const u32* wsl1 = ws + 26624;
    const u32* wsl2 = ws + 44032;
    {
        const u32x4* src = (const u32x4*)wsl1;
        u32x4* dst = (u32x4*)lds;
        for (int i = threadIdx.x; i < 4096; i += 256) {
            int ln = i & 63, fb = i >> 6, ct = fb >> 4, kb = fb & 15;
            dst[i] = src[(ct * 17 + kb) * 64 + ln];
        }
    }
    __syncthreads();

    const int lane = threadIdx.x & 63;
    const int q = lane >> 5, el = lane & 31;
    const int gw  = blockIdx.x * 4 + (threadIdx.x >> 6);
    const int gws = gridDim.x * 4;

    for (int it = gw; it < nIter; it += gws) {
        const int n0 = it * 64;
        const int nA = n0 + el, nB = n0 + 32 + el;
        const int ncA = (nA < N) ? nA : (N - 1);
        const int ncB = (nB < N) ? nB : (N - 1);
        const float* xA = x + (size_t)ncA * H;  const float* gA = buf + (size_t)ncA * H;
        const float* xB = x + (size_t)ncB * H;  const float* gB = buf + (size_t)ncB * H;

        f32x16 acc[2][4];
        #pragma unroll
        for (int s = 0; s < 2; ++s)
            #pragma unroll
            for (int ct = 0; ct < 4; ++ct) acc[s][ct] = (f32x16)0.0f;

        #pragma unroll
        for (int kb = 0; kb < 16; ++kb) {
            const int f = kb * 16 + q * 8;
            const float* pA = (f < H) ? (xA + f) : (gA + f - H);
            const float* pB = (f < H) ? (xB + f) : (gB + f - H);
            bf16x8 bA = f8frag(*(const float4*)pA, *(const float4*)(pA + 4));
            bf16x8 bB = f8frag(*(const float4*)pB, *(const float4*)(pB + 4));
            #pragma unroll
            for (int ct = 0; ct < 4; ++ct) {
                Frag a; a.u = *(const u32x4*)&lds[((ct * 16 + kb) * 64 + lane) * 4];
                acc[0][ct] = mfma(a.b, bA, acc[0][ct]);
                acc[1][ct] = mfma(a.b, bB, acc[1][ct]);
            }
        }
        {
            Frag bp; bp.u = (u32x4){0,0,0,0};
            if (q == 0) bp.u.x = 0x00003F80u;
            #pragma unroll
            for (int ct = 0; ct < 4; ++ct) {
                Frag a; a.u = *(const u32x4*)&wsl1[((size_t)(ct * 17 + 16) * 64 + lane) * 4];
                acc[0][ct] = mfma(a.b, bp.b, acc[0][ct]);
                acc[1][ct] = mfma(a.b, bp.b, acc[1][ct]);
            }
        }

        #pragma unroll
        for (int s = 0; s < 2; ++s) {
            const int nn = s ? nB : nA;
            u32 hp[4][4][2];
            #pragma unroll
            for (int ct = 0; ct < 4; ++ct)
                #pragma unroll
                for (int g = 0; g < 4; ++g) {
                    float v0 = silu(acc[s][ct][4*g + 0]);
                    float v1 = silu(acc[s][ct][4*g + 1]);
                    float v2 = silu(acc[s][ct][4*g + 2]);
                    float v3 = silu(acc[s][ct][4*g + 3]);
                    hp[ct][g][0] = pack2(v0, v1);
                    hp[ct][g][1] = pack2(v2, v3);
                }

            f32x16 acc2[4];
            #pragma unroll
            for (int ct = 0; ct < 4; ++ct) acc2[ct] = (f32x16)0.0f;

            #pragma unroll
            for (int kb2 = 0; kb2 < 8; ++kb2) {
                const int om = 2 * kb2 + q;
                const int op = 2 * kb2 + 1 - q;
                u32 sv0 = hp[op >> 2][op & 3][0];
                u32 sv1 = hp[op >> 2][op & 3][1];
                u32 r0 = (u32)__shfl((int)sv0, lane ^ 32);
                u32 r1 = (u32)__shfl((int)sv1, lane ^ 32);
                u32 w0 = hp[om >> 2][om & 3][0];
                u32 w1v = hp[om >> 2][om & 3][1];
                Frag bf;
                if (q == 0) bf.u = (u32x4){w0, w1v, r0, r1};
                else        bf.u = (u32x4){r0, r1, w0, w1v};
                #pragma unroll
                for (int ct2 = 0; ct2 < 4; ++ct2) {
                    Frag a; a.u = *(const u32x4*)&wsl2[((size_t)(ct2 * 9 + kb2) * 64 + lane) * 4];
                    acc2[ct2] = mfma(a.b, bf.b, acc2[ct2]);
                }
            }
            {
                Frag bf; bf.u = (u32x4){0,0,0,0};
                if (q == 0) bf.u.x = 0x00003F80u;
                #pragma unroll
                for (int ct2 = 0; ct2 < 4; ++ct2) {
                    Frag a; a.u = *(const u32x4*)&wsl2[((size_t)(ct2 * 9 + 8) * 64 + lane) * 4];
                    acc2[ct2] = mfma(a.b, bf.b, acc2[ct2]);
                }
            }
            if (nn < N) {
                float* orow = buf + (size_t)nn * H;
                #pragma unroll
                for (int ct2 = 0; ct2 < 4; ++ct2)
                    #pragma unroll
                    for (int g = 0; g < 4; ++g) {
                        float4 v = { acc2[ct2][4*g + 0], acc2[ct2][4*g + 1],
                                     acc2[ct2][4*g + 2], acc2[ct2][4*g + 3] };
                        *(float4*)(orow + ct2 * 32 + 8 * g + 4 * q) = v;
                    }
            }
        }
    }
}

extern "C" void kernel_launch(void* const* d_in, const int* in_sizes, int n_in,
                              void* d_out, int out_size, void* d_ws, size_t ws_size,
                              hipStream_t stream) {
    const float* x    = (const float*)d_in[0];
    const float* pos  = (const float*)d_in[1];
    const int*   ei   = (const int*)d_in[2];
    const float* mw1  = (const float*)d_in[3];
    const float* mb1  = (const float*)d_in[4];
    const float* mw2  = (const float*)d_in[5];
    const float* mb2  = (const float*)d_in[6];
    const float* uw1  = (const float*)d_in[7];
    const float* ub1  = (const float*)d_in[8];
    const float* uw2  = (const float*)d_in[9];
    const float* ub2  = (const float*)d_in[10];

    const int N = in_sizes[0] / H;
    const int E = in_sizes[2] / 2;

    // ws layout (u32 units)
    const size_t FRAGS = 53248;                  // swizzled weight frags (212,992 B)
    const size_t PO = FRAGS;                     // P: N*H fp32
    const size_t QO = PO + (size_t)N * H;        // Q: N*H fp32
    const size_t DG = QO + (size_t)N * H;        // deg: N int
    const size_t BK = DG + (size_t)N;            // bucket: N*64 int2
    const size_t ENDu = BK + (size_t)N * 128;
    const size_t need_bytes = ENDu * 4;

    u32* ws = (u32*)d_ws;
    prep_kernel<<<52, 256, 0, stream>>>(mw1, mb1, mw2, mb2, uw1, ub1, uw2, ub2, ws);

    float* buf = (float*)d_out;
    const int nIterN = (N + 63) / 64;

    if (ws_size >= need_bytes) {
        // ---- gather path: no fp32 atomics ----
        float* Pb   = (float*)(ws + PO);
        float* Qb   = (float*)(ws + QO);
        int*   deg  = (int*)(ws + DG);
        int2*  bkt  = (int2*)(ws + BK);

        pq_gemm<<<196, 256, 0, stream>>>(x, ws, Pb, 0, 0, N, nIterN);
        pq_gemm<<<196, 256, 0, stream>>>(x, ws, Qb, 8, 1, N, nIterN);

        hipMemsetAsync(deg, 0, (size_t)N * sizeof(int), stream);
        bucket_fill<<<(E + 255) / 256, 256, 0, stream>>>(pos, ei, deg, bkt, E);

        aggregate_kernel<<<1024, 256, 0, stream>>>(Pb, Qb, mw1 + 256 * H, ws + 17408,
                                                   deg, bkt, buf, N);
        node_mfma<<<256, 256, 0, stream>>>(x, buf, ws, N, nIterN);
    } else {
        // ---- fallback: round-3 atomic scatter path ----
        hipMemsetAsync(buf, 0, (size_t)N * H * sizeof(float), stream);
        edge_mfma<<<512, 256, 0, stream>>>(x, pos, ei, ws, buf, E, E / 64);
        node_mfma<<<256, 256, 0, stream>>>(x, buf, ws, N, nIterN);
    }
}

// Round 5
// 1886.738 us; speedup vs baseline: 1.8597x; 1.0510x over previous
//
#include <hip/hip_runtime.h>
#include <math.h>

#define H 128

typedef unsigned short u16;
typedef unsigned int u32;
typedef __attribute__((ext_vector_type(4))) u32 u32x4;
typedef __attribute__((ext_vector_type(8))) __bf16 bf16x8;
typedef __attribute__((ext_vector_type(16))) float f32x16;

union Frag { u32x4 u; bf16x8 b; };

__device__ __forceinline__ u16 bfr(float f) {            // f32 -> bf16 RNE
    union { float f; u32 i; } v; v.f = f;
    u32 r = v.i + 0x7fffu + ((v.i >> 16) & 1u);
    return (u16)(r >> 16);
}
__device__ __forceinline__ u32 pack2(float lo, float hi) {
    return (u32)bfr(lo) | ((u32)bfr(hi) << 16);
}
__device__ __forceinline__ float bflo(u32 w) {           // low bf16 -> f32
    union { u32 i; float f; } v; v.i = w << 16; return v.f;
}
__device__ __forceinline__ float bfhi(u32 w) {           // high bf16 -> f32
    union { u32 i; float f; } v; v.i = w & 0xffff0000u; return v.f;
}
__device__ __forceinline__ float silu(float v) {
    float e = __expf(-v);
    return v * __builtin_amdgcn_rcpf(1.0f + e);
}
__device__ __forceinline__ bf16x8 f8frag(float4 lo, float4 hi) {
    Frag f;
    f.u = (u32x4){pack2(lo.x, lo.y), pack2(lo.z, lo.w),
                  pack2(hi.x, hi.y), pack2(hi.z, hi.w)};
    return f.b;
}
__device__ __forceinline__ f32x16 mfma(bf16x8 a, bf16x8 b, f32x16 c) {
    return __builtin_amdgcn_mfma_f32_32x32x16_bf16(a, b, c, 0, 0, 0);
}

// ---------------------------------------------------------------------------
// ws frag region (u32 units):
//   mw1s @ 0      : 4ct x 17kb x 64lane x 4   (msg w1^T frags; kb16 = dist+b1 pad)
//   mw2s @ 17408  : 4ct x  9kb x 64lane x 4   (msg w2^T frags; kb8  = b2 pad)
//   uw1s @ 26624  : 4ct x 17kb x 64lane x 4   (upd w1^T frags; kb16 = b1 pad)
//   uw2s @ 44032  : 4ct x  9kb x 64lane x 4   (upd w2^T frags; kb8  = b2 pad)
// A-frag (ct,kb,lane): 8 bf16 = W[k = kb*16 + (lane>>5)*8 + j][ct*32 + (lane&31)]
// ---------------------------------------------------------------------------
__global__ void prep_kernel(const float* __restrict__ mw1, const float* __restrict__ mb1,
                            const float* __restrict__ mw2, const float* __restrict__ mb2,
                            const float* __restrict__ uw1, const float* __restrict__ ub1,
                            const float* __restrict__ uw2, const float* __restrict__ ub2,
                            u32* __restrict__ ws) {
    int t = blockIdx.x * blockDim.x + threadIdx.x;
    if (t >= 13312) return;
    const float *W, *s0, *s1;
    int nK, slot, base;
    if (t < 4352)       { W = mw1; s0 = mw1 + 256 * H; s1 = mb1; nK = 256; slot = t;         base = 0;     }
    else if (t < 6656)  { W = mw2; s0 = mb2; s1 = nullptr;       nK = 128; slot = t - 4352;  base = 17408; }
    else if (t < 11008) { W = uw1; s0 = ub1; s1 = nullptr;       nK = 256; slot = t - 6656;  base = 26624; }
    else                { W = uw2; s0 = ub2; s1 = nullptr;       nK = 128; slot = t - 11008; base = 44032; }
    int lane = slot & 63, fb = slot >> 6;
    int ct, kb;
    if (nK == 256) { ct = fb / 17; kb = fb % 17; }
    else           { ct = fb / 9;  kb = fb % 9;  }
    int m = ct * 32 + (lane & 31);
    int q = lane >> 5;
    u32 out[4];
    #pragma unroll
    for (int p = 0; p < 4; ++p) {
        float v[2];
        #pragma unroll
        for (int h = 0; h < 2; ++h) {
            int k = kb * 16 + q * 8 + p * 2 + h;
            float val = 0.0f;
            if (k < nK)            val = W[(size_t)k * H + m];
            else if (k == nK)      val = s0 ? s0[m] : 0.0f;
            else if (k == nK + 1)  val = s1 ? s1[m] : 0.0f;
            v[h] = val;
        }
        out[p] = pack2(v[0], v[1]);
    }
    u32* dst = ws + base + (size_t)slot * 4;
    dst[0] = out[0]; dst[1] = out[1]; dst[2] = out[2]; dst[3] = out[3];
}

// ---------------------------------------------------------------------------
// pq_gemm: out[n] = x[n] @ W1[kbBase*16 : +128] (+ bias row if withBias).
// packP: store rows as packed bf16 (64 u32/row); else fp32 (128 f32/row).
// ---------------------------------------------------------------------------
__global__ __launch_bounds__(256, 2) void pq_gemm(
    const float* __restrict__ x, const u32* __restrict__ mw1s,
    void* __restrict__ outp, int kbBase, int withBias, int packP, int N, int nIter)
{
    const int lane = threadIdx.x & 63;
    const int q = lane >> 5, el = lane & 31;
    const int gw  = blockIdx.x * 4 + (threadIdx.x >> 6);
    const int gws = gridDim.x * 4;

    for (int it = gw; it < nIter; it += gws) {
        const int n0 = it * 64;
        const int nA = n0 + el, nB = n0 + 32 + el;
        const int ncA = (nA < N) ? nA : (N - 1);
        const int ncB = (nB < N) ? nB : (N - 1);
        const float* xA = x + (size_t)ncA * H;
        const float* xB = x + (size_t)ncB * H;

        f32x16 acc[2][4];
        #pragma unroll
        for (int s = 0; s < 2; ++s)
            #pragma unroll
            for (int ct = 0; ct < 4; ++ct) acc[s][ct] = (f32x16)0.0f;

        #pragma unroll
        for (int kb = 0; kb < 8; ++kb) {
            const int f = kb * 16 + q * 8;
            bf16x8 bA = f8frag(*(const float4*)(xA + f), *(const float4*)(xA + f + 4));
            bf16x8 bB = f8frag(*(const float4*)(xB + f), *(const float4*)(xB + f + 4));
            #pragma unroll
            for (int ct = 0; ct < 4; ++ct) {
                Frag a; a.u = *(const u32x4*)&mw1s[((size_t)(ct * 17 + kbBase + kb) * 64 + lane) * 4];
                acc[0][ct] = mfma(a.b, bA, acc[0][ct]);
                acc[1][ct] = mfma(a.b, bB, acc[1][ct]);
            }
        }
        if (withBias) {   // pad kb16: k=256 -> 0 (skip dist row), k=257 -> 1.0 (b1)
            Frag bp; bp.u = (u32x4){0, 0, 0, 0};
            if (q == 0) bp.u.x = pack2(0.0f, 1.0f);
            #pragma unroll
            for (int ct = 0; ct < 4; ++ct) {
                Frag a; a.u = *(const u32x4*)&mw1s[((size_t)(ct * 17 + 16) * 64 + lane) * 4];
                acc[0][ct] = mfma(a.b, bp.b, acc[0][ct]);
                acc[1][ct] = mfma(a.b, bp.b, acc[1][ct]);
            }
        }
        #pragma unroll
        for (int s = 0; s < 2; ++s) {
            const int nn = s ? nB : nA;
            if (nn < N) {
                if (packP) {
                    u32* prow = (u32*)outp + (size_t)nn * 64;
                    #pragma unroll
                    for (int ct = 0; ct < 4; ++ct)
                        #pragma unroll
                        for (int g = 0; g < 4; ++g) {
                            u32 a = pack2(acc[s][ct][4*g + 0], acc[s][ct][4*g + 1]);
                            u32 b = pack2(acc[s][ct][4*g + 2], acc[s][ct][4*g + 3]);
                            *(uint2*)(prow + ct * 16 + 4 * g + 2 * q) = make_uint2(a, b);
                        }
                } else {
                    float* orow = (float*)outp + (size_t)nn * H;
                    #pragma unroll
                    for (int ct = 0; ct < 4; ++ct)
                        #pragma unroll
                        for (int g = 0; g < 4; ++g) {
                            float4 v = { acc[s][ct][4*g + 0], acc[s][ct][4*g + 1],
                                         acc[s][ct][4*g + 2], acc[s][ct][4*g + 3] };
                            *(float4*)(orow + ct * 32 + 8 * g + 4 * q) = v;
                        }
                }
            }
        }
    }
}

// ---------------------------------------------------------------------------
// bucket_fill: per edge, slot = atomicAdd(deg[rec]); bucket[rec*64+slot] = (send, dist)
// ---------------------------------------------------------------------------
__global__ void bucket_fill(const float* __restrict__ pos, const int* __restrict__ ei,
                            int* __restrict__ deg, int2* __restrict__ bucket, int E)
{
    int e = blockIdx.x * blockDim.x + threadIdx.x;
    if (e >= E) return;
    const int s = ei[e];
    const int r = ei[E + e];
    const float dx = pos[s*3]   - pos[r*3];
    const float dy = pos[s*3+1] - pos[r*3+1];
    const float dz = pos[s*3+2] - pos[r*3+2];
    const float dist = sqrtf(dx*dx + dy*dy + dz*dz);
    int slot = atomicAdd(&deg[r], 1);
    if (slot < 64) bucket[(size_t)r * 64 + slot] = make_int2(s, __float_as_int(dist));
}

// ---------------------------------------------------------------------------
// aggregate: one wave per node n.
//   h_e = silu(Pbf[send_e] + Q[n] + dist_e * wd)     (P packed bf16, unpacked)
//   msg_e = silu(h_e @ w2 + b2)                      (MFMA, b2 via pad row)
//   out[n] = sum_e msg_e                             (shfl_xor over edge lanes)
// Invalid lanes clamp to a valid slot (address reuse) but zero their B-frag.
// ---------------------------------------------------------------------------
__global__ __launch_bounds__(256, 3) void aggregate_kernel(
    const u32* __restrict__ Pbf, const float* __restrict__ Q,
    const float* __restrict__ wd, const u32* __restrict__ wsl2,
    const int* __restrict__ deg, const int2* __restrict__ bucket,
    float* __restrict__ out, int N)
{
    __shared__ u32x4 l2f[2304];                       // msg w2^T frags, 36 KiB
    for (int i = threadIdx.x; i < 2304; i += 256) l2f[i] = ((const u32x4*)wsl2)[i];
    __syncthreads();

    const int lane = threadIdx.x & 63;
    const int q = lane >> 5, el = lane & 31;
    const int gw  = blockIdx.x * 4 + (threadIdx.x >> 6);
    const int gws = gridDim.x * 4;

    for (int n = gw; n < N; n += gws) {
        int dn = deg[n]; dn = (dn > 64) ? 64 : dn;
        const int nt = (dn + 31) >> 5;
        const float* Qn = Q + (size_t)n * H;

        f32x16 acc2[4];
        #pragma unroll
        for (int ct2 = 0; ct2 < 4; ++ct2) acc2[ct2] = (f32x16)0.0f;

        for (int t = 0; t < nt; ++t) {
            const int eIdx = t * 32 + el;
            const bool valid = eIdx < dn;
            const int eC = valid ? eIdx : (dn - 1);       // clamp: reuse a valid line
            const int2 rec = bucket[(size_t)n * 64 + eC];
            const u32x4* Prow = (const u32x4*)(Pbf + (size_t)rec.x * 64);
            const float dist = __int_as_float(rec.y);

            #pragma unroll
            for (int kb2 = 0; kb2 < 8; ++kb2) {
                const int f = kb2 * 16 + q * 8;
                const u32x4 pc = Prow[kb2 * 2 + q];       // 8 bf16 of P row
                const float4 q0 = *(const float4*)(Qn + f);
                const float4 q1 = *(const float4*)(Qn + f + 4);
                const float4 w0 = *(const float4*)(wd + f);
                const float4 w1 = *(const float4*)(wd + f + 4);
                const float v0 = silu(bflo(pc.x) + q0.x + dist * w0.x);
                const float v1 = silu(bfhi(pc.x) + q0.y + dist * w0.y);
                const float v2 = silu(bflo(pc.y) + q0.z + dist * w0.z);
                const float v3 = silu(bfhi(pc.y) + q0.w + dist * w0.w);
                const float v4 = silu(bflo(pc.z) + q1.x + dist * w1.x);
                const float v5 = silu(bfhi(pc.z) + q1.y + dist * w1.y);
                const float v6 = silu(bflo(pc.w) + q1.z + dist * w1.z);
                const float v7 = silu(bfhi(pc.w) + q1.w + dist * w1.w);
                Frag bf;
                bf.u = (u32x4){pack2(v0, v1), pack2(v2, v3), pack2(v4, v5), pack2(v6, v7)};
                if (!valid) bf.u = (u32x4){0, 0, 0, 0};
                #pragma unroll
                for (int ct2 = 0; ct2 < 4; ++ct2) {
                    Frag a; a.u = l2f[(ct2 * 9 + kb2) * 64 + lane];
                    acc2[ct2] = mfma(a.b, bf.b, acc2[ct2]);
                }
            }
            {   // pad kb2=8: k=128 -> 1.0 (b2 row), valid edges only
                Frag bf; bf.u = (u32x4){0, 0, 0, 0};
                if (valid && q == 0) bf.u.x = 0x00003F80u;
                #pragma unroll
                for (int ct2 = 0; ct2 < 4; ++ct2) {
                    Frag a; a.u = l2f[(ct2 * 9 + 8) * 64 + lane];
                    acc2[ct2] = mfma(a.b, bf.b, acc2[ct2]);
                }
            }
        }

        // silu -> sum over 32 edge lanes -> one masked float4 store per (ct2,g)
        float* orow = out + (size_t)n * H;
        #pragma unroll
        for (int ct2 = 0; ct2 < 4; ++ct2)
            #pragma unroll
            for (int g = 0; g < 4; ++g) {
                float4 sv;
                #pragma unroll
                for (int j = 0; j < 4; ++j) {
                    float m = silu(acc2[ct2][4*g + j]);
                    m += __shfl_xor(m, 1);
                    m += __shfl_xor(m, 2);
                    m += __shfl_xor(m, 4);
                    m += __shfl_xor(m, 8);
                    m += __shfl_xor(m, 16);
                    ((float*)&sv)[j] = m;
                }
                if (el == 0) *(float4*)(orow + ct2 * 32 + 8 * g + 4 * q) = sv;
            }
    }
}

// ---------------------------------------------------------------------------
// FALLBACK (ws too small): round-3 edge kernel with fp32 atomics.
// ---------------------------------------------------------------------------
__global__ __launch_bounds__(256, 2) void edge_mfma(
    const float* __restrict__ x, const float* __restrict__ pos,
    const int* __restrict__ ei, const u32* __restrict__ ws,
    float* __restrict__ aggr, int E, int nIter)
{
    __shared__ u32 lds[16384];
    {
        const u32x4* src = (const u32x4*)ws;
        u32x4* dst = (u32x4*)lds;
        for (int i = threadIdx.x; i < 4096; i += 256) {
            int ln = i & 63, fb = i >> 6, ct = fb >> 4, kb = fb & 15;
            dst[i] = src[(ct * 17 + kb) * 64 + ln];
        }
    }
    __syncthreads();
    const u32* wsl1 = ws;
    const u32* wsl2 = ws + 17408;

    const int lane = threadIdx.x & 63;
    const int q = lane >> 5, el = lane & 31;
    const int gw  = blockIdx.x * 4 + (threadIdx.x >> 6);
    const int gws = gridDim.x * 4;

    for (int it = gw; it < nIter; it += gws) {
        const int e0 = it * 64;
        const int sA = ei[e0 + el],      rA = ei[E + e0 + el];
        const int sB = ei[e0 + 32 + el], rB = ei[E + e0 + 32 + el];
        float dA, dB;
        {
            float ax = pos[sA*3] - pos[rA*3], ay = pos[sA*3+1] - pos[rA*3+1], az = pos[sA*3+2] - pos[rA*3+2];
            dA = sqrtf(ax*ax + ay*ay + az*az);
            float bx = pos[sB*3] - pos[rB*3], by = pos[sB*3+1] - pos[rB*3+1], bz = pos[sB*3+2] - pos[rB*3+2];
            dB = sqrtf(bx*bx + by*by + bz*bz);
        }
        const float* xsA = x + (size_t)sA * H; const float* xrA = x + (size_t)rA * H;
        const float* xsB = x + (size_t)sB * H; const float* xrB = x + (size_t)rB * H;

        f32x16 acc[2][4];
        #pragma unroll
        for (int s = 0; s < 2; ++s)
            #pragma unroll
            for (int ct = 0; ct < 4; ++ct) acc[s][ct] = (f32x16)0.0f;

        #pragma unroll
        for (int kb = 0; kb < 16; ++kb) {
            const int f = kb * 16 + q * 8;
            const float* pA = (f < H) ? (xsA + f) : (xrA + f - H);
            const float* pB = (f < H) ? (xsB + f) : (xrB + f - H);
            bf16x8 bA = f8frag(*(const float4*)pA, *(const float4*)(pA + 4));
            bf16x8 bB = f8frag(*(const float4*)pB, *(const float4*)(pB + 4));
            #pragma unroll
            for (int ct = 0; ct < 4; ++ct) {
                Frag a; a.u = *(const u32x4*)&lds[((ct * 16 + kb) * 64 + lane) * 4];
                acc[0][ct] = mfma(a.b, bA, acc[0][ct]);
                acc[1][ct] = mfma(a.b, bB, acc[1][ct]);
            }
        }
        {
            Frag bA, bB;
            bA.u = (u32x4){0,0,0,0}; bB.u = (u32x4){0,0,0,0};
            if (q == 0) { bA.u.x = pack2(dA, 1.0f); bB.u.x = pack2(dB, 1.0f); }
            #pragma unroll
            for (int ct = 0; ct < 4; ++ct) {
                Frag a; a.u = *(const u32x4*)&wsl1[((size_t)(ct * 17 + 16) * 64 + lane) * 4];
                acc[0][ct] = mfma(a.b, bA.b, acc[0][ct]);
                acc[1][ct] = mfma(a.b, bB.b, acc[1][ct]);
            }
        }

        #pragma unroll
        for (int s = 0; s < 2; ++s) {
            const int ridx = s ? rB : rA;
            u32 hp[4][4][2];
            #pragma unroll
            for (int ct = 0; ct < 4; ++ct)
                #pragma unroll
                for (int g = 0; g < 4; ++g) {
                    float v0 = silu(acc[s][ct][4*g + 0]);
                    float v1 = silu(acc[s][ct][4*g + 1]);
                    float v2 = silu(acc[s][ct][4*g + 2]);
                    float v3 = silu(acc[s][ct][4*g + 3]);
                    hp[ct][g][0] = pack2(v0, v1);
                    hp[ct][g][1] = pack2(v2, v3);
                }

            f32x16 acc2[4];
            #pragma unroll
            for (int ct = 0; ct < 4; ++ct) acc2[ct] = (f32x16)0.0f;

            #pragma unroll
            for (int kb2 = 0; kb2 < 8; ++kb2) {
                const int om = 2 * kb2 + q;
                const int op = 2 * kb2 + 1 - q;
                u32 sv0 = hp[op >> 2][op & 3][0];
                u32 sv1 = hp[op >> 2][op & 3][1];
                u32 r0 = (u32)__shfl((int)sv0, lane ^ 32);
                u32 r1 = (u32)__shfl((int)sv1, lane ^ 32);
                u32 w0 = hp[om >> 2][om & 3][0];
                u32 w1v = hp[om >> 2][om & 3][1];
                Frag bf;
                if (q == 0) bf.u = (u32x4){w0, w1v, r0, r1};
                else        bf.u = (u32x4){r0, r1, w0, w1v};
                #pragma unroll
                for (int ct2 = 0; ct2 < 4; ++ct2) {
                    Frag a; a.u = *(const u32x4*)&wsl2[((size_t)(ct2 * 9 + kb2) * 64 + lane) * 4];
                    acc2[ct2] = mfma(a.b, bf.b, acc2[ct2]);
                }
            }
            {
                Frag bf; bf.u = (u32x4){0,0,0,0};
                if (q == 0) bf.u.x = 0x00003F80u;
                #pragma unroll
                for (int ct2 = 0; ct2 < 4; ++ct2) {
                    Frag a; a.u = *(const u32x4*)&wsl2[((size_t)(ct2 * 9 + 8) * 64 + lane) * 4];
                    acc2[ct2] = mfma(a.b, bf.b, acc2[ct2]);
                }
            }
            float* arow = aggr + (size_t)ridx * H;
            #pragma unroll
            for (int ct2 = 0; ct2 < 4; ++ct2)
                #pragma unroll
                for (int r = 0; r < 16; ++r) {
                    int m = ct2 * 32 + (r & 3) + 8 * (r >> 2) + 4 * q;
                    atomicAdd(arow + m, silu(acc2[ct2][r]));
                }
        }
    }
}

// ---------------------------------------------------------------------------
// Node update MLP: update = silu([x, aggr] @ uw1 + ub1) @ uw2 + ub2
// buf == d_out: aggr rows on entry, overwritten with the final update.
// ---------------------------------------------------------------------------
__global__ __launch_bounds__(256, 2) void node_mfma(
    const float* __restrict__ x, float* __restrict__ buf,
    const u32* __restrict__ ws, int N, int nIter)
{
    __shared__ u32 lds[16384];
    const u32* wsl1 = ws + 26624;
    const u32* wsl2 = ws + 44032;
    {
        const u32x4* src = (const u32x4*)wsl1;
        u32x4* dst = (u32x4*)lds;
        for (int i = threadIdx.x; i < 4096; i += 256) {
            int ln = i & 63, fb = i >> 6, ct = fb >> 4, kb = fb & 15;
            dst[i] = src[(ct * 17 + kb) * 64 + ln];
        }
    }
    __syncthreads();

    const int lane = threadIdx.x & 63;
    const int q = lane >> 5, el = lane & 31;
    const int gw  = blockIdx.x * 4 + (threadIdx.x >> 6);
    const int gws = gridDim.x * 4;

    for (int it = gw; it < nIter; it += gws) {
        const int n0 = it * 64;
        const int nA = n0 + el, nB = n0 + 32 + el;
        const int ncA = (nA < N) ? nA : (N - 1);
        const int ncB = (nB < N) ? nB : (N - 1);
        const float* xA = x + (size_t)ncA * H;  const float* gA = buf + (size_t)ncA * H;
        const float* xB = x + (size_t)ncB * H;  const float* gB = buf + (size_t)ncB * H;

        f32x16 acc[2][4];
        #pragma unroll
        for (int s = 0; s < 2; ++s)
            #pragma unroll
            for (int ct = 0; ct < 4; ++ct) acc[s][ct] = (f32x16)0.0f;

        #pragma unroll
        for (int kb = 0; kb < 16; ++kb) {
            const int f = kb * 16 + q * 8;
            const float* pA = (f < H) ? (xA + f) : (gA + f - H);
            const float* pB = (f < H) ? (xB + f) : (gB + f - H);
            bf16x8 bA = f8frag(*(const float4*)pA, *(const float4*)(pA + 4));
            bf16x8 bB = f8frag(*(const float4*)pB, *(const float4*)(pB + 4));
            #pragma unroll
            for (int ct = 0; ct < 4; ++ct) {
                Frag a; a.u = *(const u32x4*)&lds[((ct * 16 + kb) * 64 + lane) * 4];
                acc[0][ct] = mfma(a.b, bA, acc[0][ct]);
                acc[1][ct] = mfma(a.b, bB, acc[1][ct]);
            }
        }
        {
            Frag bp; bp.u = (u32x4){0,0,0,0};
            if (q == 0) bp.u.x = 0x00003F80u;
            #pragma unroll
            for (int ct = 0; ct < 4; ++ct) {
                Frag a; a.u = *(const u32x4*)&wsl1[((size_t)(ct * 17 + 16) * 64 + lane) * 4];
                acc[0][ct] = mfma(a.b, bp.b, acc[0][ct]);
                acc[1][ct] = mfma(a.b, bp.b, acc[1][ct]);
            }
        }

        #pragma unroll
        for (int s = 0; s < 2; ++s) {
            const int nn = s ? nB : nA;
            u32 hp[4][4][2];
            #pragma unroll
            for (int ct = 0; ct < 4; ++ct)
                #pragma unroll
                for (int g = 0; g < 4; ++g) {
                    float v0 = silu(acc[s][ct][4*g + 0]);
                    float v1 = silu(acc[s][ct][4*g + 1]);
                    float v2 = silu(acc[s][ct][4*g + 2]);
                    float v3 = silu(acc[s][ct][4*g + 3]);
                    hp[ct][g][0] = pack2(v0, v1);
                    hp[ct][g][1] = pack2(v2, v3);
                }

            f32x16 acc2[4];
            #pragma unroll
            for (int ct = 0; ct < 4; ++ct) acc2[ct] = (f32x16)0.0f;

            #pragma unroll
            for (int kb2 = 0; kb2 < 8; ++kb2) {
                const int om = 2 * kb2 + q;
                const int op = 2 * kb2 + 1 - q;
                u32 sv0 = hp[op >> 2][op & 3][0];
                u32 sv1 = hp[op >> 2][op & 3][1];
                u32 r0 = (u32)__shfl((int)sv0, lane ^ 32);
                u32 r1 = (u32)__shfl((int)sv1, lane ^ 32);
                u32 w0 = hp[om >> 2][om & 3][0];
                u32 w1v = hp[om >> 2][om & 3][1];
                Frag bf;
                if (q == 0) bf.u = (u32x4){w0, w1v, r0, r1};
                else        bf.u = (u32x4){r0, r1, w0, w1v};
                #pragma unroll
                for (int ct2 = 0; ct2 < 4; ++ct2) {
                    Frag a; a.u = *(const u32x4*)&wsl2[((size_t)(ct2 * 9 + kb2) * 64 + lane) * 4];
                    acc2[ct2] = mfma(a.b, bf.b, acc2[ct2]);
                }
            }
            {
                Frag bf; bf.u = (u32x4){0,0,0,0};
                if (q == 0) bf.u.x = 0x00003F80u;
                #pragma unroll
                for (int ct2 = 0; ct2 < 4; ++ct2) {
                    Frag a; a.u = *(const u32x4*)&wsl2[((size_t)(ct2 * 9 + 8) * 64 + lane) * 4];
                    acc2[ct2] = mfma(a.b, bf.b, acc2[ct2]);
                }
            }
            if (nn < N) {
                float* orow = buf + (size_t)nn * H;
                #pragma unroll
                for (int ct2 = 0; ct2 < 4; ++ct2)
                    #pragma unroll
                    for (int g = 0; g < 4; ++g) {
                        float4 v = { acc2[ct2][4*g + 0], acc2[ct2][4*g + 1],
                                     acc2[ct2][4*g + 2], acc2[ct2][4*g + 3] };
                        *(float4*)(orow + ct2 * 32 + 8 * g + 4 * q) = v;
                    }
            }
        }
    }
}

extern "C" void kernel_launch(void* const* d_in, const int* in_sizes, int n_in,
                              void* d_out, int out_size, void* d_ws, size_t ws_size,
                              hipStream_t stream) {
    const float* x    = (const float*)d_in[0];
    const float* pos  = (const float*)d_in[1];
    const int*   ei   = (const int*)d_in[2];
    const float* mw1  = (const float*)d_in[3];
    const float* mb1  = (const float*)d_in[4];
    const float* mw2  = (const float*)d_in[5];
    const float* mb2  = (const float*)d_in[6];
    const float* uw1  = (const float*)d_in[7];
    const float* ub1  = (const float*)d_in[8];
    const float* uw2  = (const float*)d_in[9];
    const float* ub2  = (const float*)d_in[10];

    const int N = in_sizes[0] / H;
    const int E = in_sizes[2] / 2;

    // ws layout (u32 units)
    const size_t FRAGS = 53248;                  // swizzled weight frags
    const size_t PO = FRAGS;                     // P: N*64 u32 (packed bf16 rows)
    const size_t QO = PO + (size_t)N * 64;       // Q: N*H fp32
    const size_t DG = QO + (size_t)N * H;        // deg: N int
    const size_t BK = DG + (size_t)N;            // bucket: N*64 int2
    const size_t ENDu = BK + (size_t)N * 128;
    const size_t need_bytes = ENDu * 4;

    u32* ws = (u32*)d_ws;
    prep_kernel<<<52, 256, 0, stream>>>(mw1, mb1, mw2, mb2, uw1, ub1, uw2, ub2, ws);

    float* buf = (float*)d_out;
    const int nIterN = (N + 63) / 64;

    if (ws_size >= need_bytes) {
        // ---- gather path: no fp32 atomics ----
        u32*   Pb   = ws + PO;
        float* Qb   = (float*)(ws + QO);
        int*   deg  = (int*)(ws + DG);
        int2*  bkt  = (int2*)(ws + BK);

        pq_gemm<<<196, 256, 0, stream>>>(x, ws, Pb, 0, 0, 1, N, nIterN);
        pq_gemm<<<196, 256, 0, stream>>>(x, ws, Qb, 8, 1, 0, N, nIterN);

        hipMemsetAsync(deg, 0, (size_t)N * sizeof(int), stream);
        bucket_fill<<<(E + 255) / 256, 256, 0, stream>>>(pos, ei, deg, bkt, E);

        aggregate_kernel<<<1024, 256, 0, stream>>>(Pb, Qb, mw1 + 256 * H, ws + 17408,
                                                   deg, bkt, buf, N);
        node_mfma<<<256, 256, 0, stream>>>(x, buf, ws, N, nIterN);
    } else {
        // ---- fallback: round-3 atomic scatter path ----
        hipMemsetAsync(buf, 0, (size_t)N * H * sizeof(float), stream);
        edge_mfma<<<512, 256, 0, stream>>>(x, pos, ei, ws, buf, E, E / 64);
        node_mfma<<<256, 256, 0, stream>>>(x, buf, ws, N, nIterN);
    }
}

// Round 6
// 565.054 us; speedup vs baseline: 6.2097x; 3.3390x over previous
//
#include <hip/hip_runtime.h>
#include <math.h>

#define H 128

typedef unsigned short u16;
typedef unsigned int u32;
typedef __attribute__((ext_vector_type(4))) u32 u32x4;
typedef __attribute__((ext_vector_type(8))) __bf16 bf16x8;
typedef __attribute__((ext_vector_type(16))) float f32x16;

union Frag { u32x4 u; bf16x8 b; };

__device__ __forceinline__ u16 bfr(float f) {            // f32 -> bf16 RNE
    union { float f; u32 i; } v; v.f = f;
    u32 r = v.i + 0x7fffu + ((v.i >> 16) & 1u);
    return (u16)(r >> 16);
}
__device__ __forceinline__ u32 pack2(float lo, float hi) {
    return (u32)bfr(lo) | ((u32)bfr(hi) << 16);
}
__device__ __forceinline__ float bflo(u32 w) {           // low bf16 -> f32
    union { u32 i; float f; } v; v.i = w << 16; return v.f;
}
__device__ __forceinline__ float bfhi(u32 w) {           // high bf16 -> f32
    union { u32 i; float f; } v; v.i = w & 0xffff0000u; return v.f;
}
__device__ __forceinline__ float silu(float v) {
    float e = __expf(-v);
    return v * __builtin_amdgcn_rcpf(1.0f + e);
}
__device__ __forceinline__ bf16x8 f8frag(float4 lo, float4 hi) {
    Frag f;
    f.u = (u32x4){pack2(lo.x, lo.y), pack2(lo.z, lo.w),
                  pack2(hi.x, hi.y), pack2(hi.z, hi.w)};
    return f.b;
}
__device__ __forceinline__ f32x16 mfma(bf16x8 a, bf16x8 b, f32x16 c) {
    return __builtin_amdgcn_mfma_f32_32x32x16_bf16(a, b, c, 0, 0, 0);
}

// ---------------------------------------------------------------------------
// ws frag region (u32 units):
//   mw1s @ 0      : 4ct x 17kb x 64lane x 4   (msg w1^T frags; kb16 = dist+b1 pad)
//   mw2s @ 17408  : 4ct x  9kb x 64lane x 4   (msg w2^T frags; kb8  = b2 pad)
//   uw1s @ 26624  : 4ct x 17kb x 64lane x 4   (upd w1^T frags; kb16 = b1 pad)
//   uw2s @ 44032  : 4ct x  9kb x 64lane x 4   (upd w2^T frags; kb8  = b2 pad)
// A-frag (ct,kb,lane): 8 bf16 = W[k = kb*16 + (lane>>5)*8 + j][ct*32 + (lane&31)]
// ---------------------------------------------------------------------------
__global__ void prep_kernel(const float* __restrict__ mw1, const float* __restrict__ mb1,
                            const float* __restrict__ mw2, const float* __restrict__ mb2,
                            const float* __restrict__ uw1, const float* __restrict__ ub1,
                            const float* __restrict__ uw2, const float* __restrict__ ub2,
                            u32* __restrict__ ws) {
    int t = blockIdx.x * blockDim.x + threadIdx.x;
    if (t >= 13312) return;
    const float *W, *s0, *s1;
    int nK, slot, base;
    if (t < 4352)       { W = mw1; s0 = mw1 + 256 * H; s1 = mb1; nK = 256; slot = t;         base = 0;     }
    else if (t < 6656)  { W = mw2; s0 = mb2; s1 = nullptr;       nK = 128; slot = t - 4352;  base = 17408; }
    else if (t < 11008) { W = uw1; s0 = ub1; s1 = nullptr;       nK = 256; slot = t - 6656;  base = 26624; }
    else                { W = uw2; s0 = ub2; s1 = nullptr;       nK = 128; slot = t - 11008; base = 44032; }
    int lane = slot & 63, fb = slot >> 6;
    int ct, kb;
    if (nK == 256) { ct = fb / 17; kb = fb % 17; }
    else           { ct = fb / 9;  kb = fb % 9;  }
    int m = ct * 32 + (lane & 31);
    int q = lane >> 5;
    u32 out[4];
    #pragma unroll
    for (int p = 0; p < 4; ++p) {
        float v[2];
        #pragma unroll
        for (int h = 0; h < 2; ++h) {
            int k = kb * 16 + q * 8 + p * 2 + h;
            float val = 0.0f;
            if (k < nK)            val = W[(size_t)k * H + m];
            else if (k == nK)      val = s0 ? s0[m] : 0.0f;
            else if (k == nK + 1)  val = s1 ? s1[m] : 0.0f;
            v[h] = val;
        }
        out[p] = pack2(v[0], v[1]);
    }
    u32* dst = ws + base + (size_t)slot * 4;
    dst[0] = out[0]; dst[1] = out[1]; dst[2] = out[2]; dst[3] = out[3];
}

// ---------------------------------------------------------------------------
// pq_gemm: out[n] = x[n] @ W1[kbBase*16 : +128] (+ bias row if withBias).
// packP: store rows as packed bf16 (64 u32/row); else fp32 (128 f32/row).
// ---------------------------------------------------------------------------
__global__ __launch_bounds__(256, 2) void pq_gemm(
    const float* __restrict__ x, const u32* __restrict__ mw1s,
    void* __restrict__ outp, int kbBase, int withBias, int packP, int N, int nIter)
{
    const int lane = threadIdx.x & 63;
    const int q = lane >> 5, el = lane & 31;
    const int gw  = blockIdx.x * 4 + (threadIdx.x >> 6);
    const int gws = gridDim.x * 4;

    for (int it = gw; it < nIter; it += gws) {
        const int n0 = it * 64;
        const int nA = n0 + el, nB = n0 + 32 + el;
        const int ncA = (nA < N) ? nA : (N - 1);
        const int ncB = (nB < N) ? nB : (N - 1);
        const float* xA = x + (size_t)ncA * H;
        const float* xB = x + (size_t)ncB * H;

        f32x16 acc[2][4];
        #pragma unroll
        for (int s = 0; s < 2; ++s)
            #pragma unroll
            for (int ct = 0; ct < 4; ++ct) acc[s][ct] = (f32x16)0.0f;

        #pragma unroll
        for (int kb = 0; kb < 8; ++kb) {
            const int f = kb * 16 + q * 8;
            bf16x8 bA = f8frag(*(const float4*)(xA + f), *(const float4*)(xA + f + 4));
            bf16x8 bB = f8frag(*(const float4*)(xB + f), *(const float4*)(xB + f + 4));
            #pragma unroll
            for (int ct = 0; ct < 4; ++ct) {
                Frag a; a.u = *(const u32x4*)&mw1s[((size_t)(ct * 17 + kbBase + kb) * 64 + lane) * 4];
                acc[0][ct] = mfma(a.b, bA, acc[0][ct]);
                acc[1][ct] = mfma(a.b, bB, acc[1][ct]);
            }
        }
        if (withBias) {   // pad kb16: k=256 -> 0 (skip dist row), k=257 -> 1.0 (b1)
            Frag bp; bp.u = (u32x4){0, 0, 0, 0};
            if (q == 0) bp.u.x = pack2(0.0f, 1.0f);
            #pragma unroll
            for (int ct = 0; ct < 4; ++ct) {
                Frag a; a.u = *(const u32x4*)&mw1s[((size_t)(ct * 17 + 16) * 64 + lane) * 4];
                acc[0][ct] = mfma(a.b, bp.b, acc[0][ct]);
                acc[1][ct] = mfma(a.b, bp.b, acc[1][ct]);
            }
        }
        #pragma unroll
        for (int s = 0; s < 2; ++s) {
            const int nn = s ? nB : nA;
            if (nn < N) {
                if (packP) {
                    u32* prow = (u32*)outp + (size_t)nn * 64;
                    #pragma unroll
                    for (int ct = 0; ct < 4; ++ct)
                        #pragma unroll
                        for (int g = 0; g < 4; ++g) {
                            u32 a = pack2(acc[s][ct][4*g + 0], acc[s][ct][4*g + 1]);
                            u32 b = pack2(acc[s][ct][4*g + 2], acc[s][ct][4*g + 3]);
                            *(uint2*)(prow + ct * 16 + 4 * g + 2 * q) = make_uint2(a, b);
                        }
                } else {
                    float* orow = (float*)outp + (size_t)nn * H;
                    #pragma unroll
                    for (int ct = 0; ct < 4; ++ct)
                        #pragma unroll
                        for (int g = 0; g < 4; ++g) {
                            float4 v = { acc[s][ct][4*g + 0], acc[s][ct][4*g + 1],
                                         acc[s][ct][4*g + 2], acc[s][ct][4*g + 3] };
                            *(float4*)(orow + ct * 32 + 8 * g + 4 * q) = v;
                        }
                }
            }
        }
    }
}

// ---------------------------------------------------------------------------
// bucket_fill: per edge, slot = atomicAdd(deg[rec]); bucket[rec*64+slot] = (send, dist)
// ---------------------------------------------------------------------------
__global__ void bucket_fill(const float* __restrict__ pos, const int* __restrict__ ei,
                            int* __restrict__ deg, int2* __restrict__ bucket, int E)
{
    int e = blockIdx.x * blockDim.x + threadIdx.x;
    if (e >= E) return;
    const int s = ei[e];
    const int r = ei[E + e];
    const float dx = pos[s*3]   - pos[r*3];
    const float dy = pos[s*3+1] - pos[r*3+1];
    const float dz = pos[s*3+2] - pos[r*3+2];
    const float dist = sqrtf(dx*dx + dy*dy + dz*dz);
    int slot = atomicAdd(&deg[r], 1);
    if (slot < 64) bucket[(size_t)r * 64 + slot] = make_int2(s, __float_as_int(dist));
}

// ---------------------------------------------------------------------------
// aggregate: one wave per node n.
//   h_e = silu(Pbf[send_e] + Q[n] + dist_e * wd)     (P packed bf16, unpacked)
//   msg_e = silu(h_e @ w2 + b2)                      (MFMA, b2 via pad row)
//   out[n] = sum_e msg_e                             (shfl_xor over edge lanes)
// Invalid lanes clamp to a valid slot (address reuse) but zero their B-frag.
// __launch_bounds__(256,2): 256-reg unified cap — acc2 (64) + working set must
// NOT spill (R5's (256,3)/170-cap version spilled -> 4.9 GB scratch traffic).
// #pragma unroll 4 on kb2 limits hoisted-load transient pressure.
// ---------------------------------------------------------------------------
__global__ __launch_bounds__(256, 2) void aggregate_kernel(
    const u32* __restrict__ Pbf, const float* __restrict__ Q,
    const float* __restrict__ wd, const u32* __restrict__ wsl2,
    const int* __restrict__ deg, const int2* __restrict__ bucket,
    float* __restrict__ out, int N)
{
    __shared__ u32x4 l2f[2304];                       // msg w2^T frags, 36 KiB
    for (int i = threadIdx.x; i < 2304; i += 256) l2f[i] = ((const u32x4*)wsl2)[i];
    __syncthreads();

    const int lane = threadIdx.x & 63;
    const int q = lane >> 5, el = lane & 31;
    const int gw  = blockIdx.x * 4 + (threadIdx.x >> 6);
    const int gws = gridDim.x * 4;

    for (int n = gw; n < N; n += gws) {
        int dn = deg[n]; dn = (dn > 64) ? 64 : dn;
        const int nt = (dn + 31) >> 5;
        const float* Qn = Q + (size_t)n * H;

        f32x16 acc2[4];
        #pragma unroll
        for (int ct2 = 0; ct2 < 4; ++ct2) acc2[ct2] = (f32x16)0.0f;

        for (int t = 0; t < nt; ++t) {
            const int eIdx = t * 32 + el;
            const bool valid = eIdx < dn;
            const int eC = valid ? eIdx : (dn - 1);       // clamp: reuse a valid line
            const int2 rec = bucket[(size_t)n * 64 + eC];
            const u32x4* Prow = (const u32x4*)(Pbf + (size_t)rec.x * 64);
            const float dist = __int_as_float(rec.y);

            #pragma unroll 4
            for (int kb2 = 0; kb2 < 8; ++kb2) {
                const int f = kb2 * 16 + q * 8;
                const u32x4 pc = Prow[kb2 * 2 + q];       // 8 bf16 of P row
                const float4 q0 = *(const float4*)(Qn + f);
                const float4 q1 = *(const float4*)(Qn + f + 4);
                const float4 w0 = *(const float4*)(wd + f);
                const float4 w1 = *(const float4*)(wd + f + 4);
                const float v0 = silu(bflo(pc.x) + q0.x + dist * w0.x);
                const float v1 = silu(bfhi(pc.x) + q0.y + dist * w0.y);
                const float v2 = silu(bflo(pc.y) + q0.z + dist * w0.z);
                const float v3 = silu(bfhi(pc.y) + q0.w + dist * w0.w);
                const float v4 = silu(bflo(pc.z) + q1.x + dist * w1.x);
                const float v5 = silu(bfhi(pc.z) + q1.y + dist * w1.y);
                const float v6 = silu(bflo(pc.w) + q1.z + dist * w1.z);
                const float v7 = silu(bfhi(pc.w) + q1.w + dist * w1.w);
                Frag bf;
                bf.u = (u32x4){pack2(v0, v1), pack2(v2, v3), pack2(v4, v5), pack2(v6, v7)};
                if (!valid) bf.u = (u32x4){0, 0, 0, 0};
                #pragma unroll
                for (int ct2 = 0; ct2 < 4; ++ct2) {
                    Frag a; a.u = l2f[(ct2 * 9 + kb2) * 64 + lane];
                    acc2[ct2] = mfma(a.b, bf.b, acc2[ct2]);
                }
            }
            {   // pad kb2=8: k=128 -> 1.0 (b2 row), valid edges only
                Frag bf; bf.u = (u32x4){0, 0, 0, 0};
                if (valid && q == 0) bf.u.x = 0x00003F80u;
                #pragma unroll
                for (int ct2 = 0; ct2 < 4; ++ct2) {
                    Frag a; a.u = l2f[(ct2 * 9 + 8) * 64 + lane];
                    acc2[ct2] = mfma(a.b, bf.b, acc2[ct2]);
                }
            }
        }

        // silu -> sum over 32 edge lanes -> one masked float4 store per (ct2,g)
        float* orow = out + (size_t)n * H;
        #pragma unroll
        for (int ct2 = 0; ct2 < 4; ++ct2)
            #pragma unroll
            for (int g = 0; g < 4; ++g) {
                float4 sv;
                #pragma unroll
                for (int j = 0; j < 4; ++j) {
                    float m = silu(acc2[ct2][4*g + j]);
                    m += __shfl_xor(m, 1);
                    m += __shfl_xor(m, 2);
                    m += __shfl_xor(m, 4);
                    m += __shfl_xor(m, 8);
                    m += __shfl_xor(m, 16);
                    ((float*)&sv)[j] = m;
                }
                if (el == 0) *(float4*)(orow + ct2 * 32 + 8 * g + 4 * q) = sv;
            }
    }
}

// ---------------------------------------------------------------------------
// FALLBACK (ws too small): round-3 edge kernel with fp32 atomics.
// ---------------------------------------------------------------------------
__global__ __launch_bounds__(256, 2) void edge_mfma(
    const float* __restrict__ x, const float* __restrict__ pos,
    const int* __restrict__ ei, const u32* __restrict__ ws,
    float* __restrict__ aggr, int E, int nIter)
{
    __shared__ u32 lds[16384];
    {
        const u32x4* src = (const u32x4*)ws;
        u32x4* dst = (u32x4*)lds;
        for (int i = threadIdx.x; i < 4096; i += 256) {
            int ln = i & 63, fb = i >> 6, ct = fb >> 4, kb = fb & 15;
            dst[i] = src[(ct * 17 + kb) * 64 + ln];
        }
    }
    __syncthreads();
    const u32* wsl1 = ws;
    const u32* wsl2 = ws + 17408;

    const int lane = threadIdx.x & 63;
    const int q = lane >> 5, el = lane & 31;
    const int gw  = blockIdx.x * 4 + (threadIdx.x >> 6);
    const int gws = gridDim.x * 4;

    for (int it = gw; it < nIter; it += gws) {
        const int e0 = it * 64;
        const int sA = ei[e0 + el],      rA = ei[E + e0 + el];
        const int sB = ei[e0 + 32 + el], rB = ei[E + e0 + 32 + el];
        float dA, dB;
        {
            float ax = pos[sA*3] - pos[rA*3], ay = pos[sA*3+1] - pos[rA*3+1], az = pos[sA*3+2] - pos[rA*3+2];
            dA = sqrtf(ax*ax + ay*ay + az*az);
            float bx = pos[sB*3] - pos[rB*3], by = pos[sB*3+1] - pos[rB*3+1], bz = pos[sB*3+2] - pos[rB*3+2];
            dB = sqrtf(bx*bx + by*by + bz*bz);
        }
        const float* xsA = x + (size_t)sA * H; const float* xrA = x + (size_t)rA * H;
        const float* xsB = x + (size_t)sB * H; const float* xrB = x + (size_t)rB * H;

        f32x16 acc[2][4];
        #pragma unroll
        for (int s = 0; s < 2; ++s)
            #pragma unroll
            for (int ct = 0; ct < 4; ++ct) acc[s][ct] = (f32x16)0.0f;

        #pragma unroll
        for (int kb = 0; kb < 16; ++kb) {
            const int f = kb * 16 + q * 8;
            const float* pA = (f < H) ? (xsA + f) : (xrA + f - H);
            const float* pB = (f < H) ? (xsB + f) : (xrB + f - H);
            bf16x8 bA = f8frag(*(const float4*)pA, *(const float4*)(pA + 4));
            bf16x8 bB = f8frag(*(const float4*)pB, *(const float4*)(pB + 4));
            #pragma unroll
            for (int ct = 0; ct < 4; ++ct) {
                Frag a; a.u = *(const u32x4*)&lds[((ct * 16 + kb) * 64 + lane) * 4];
                acc[0][ct] = mfma(a.b, bA, acc[0][ct]);
                acc[1][ct] = mfma(a.b, bB, acc[1][ct]);
            }
        }
        {
            Frag bA, bB;
            bA.u = (u32x4){0,0,0,0}; bB.u = (u32x4){0,0,0,0};
            if (q == 0) { bA.u.x = pack2(dA, 1.0f); bB.u.x = pack2(dB, 1.0f); }
            #pragma unroll
            for (int ct = 0; ct < 4; ++ct) {
                Frag a; a.u = *(const u32x4*)&wsl1[((size_t)(ct * 17 + 16) * 64 + lane) * 4];
                acc[0][ct] = mfma(a.b, bA.b, acc[0][ct]);
                acc[1][ct] = mfma(a.b, bB.b, acc[1][ct]);
            }
        }

        #pragma unroll
        for (int s = 0; s < 2; ++s) {
            const int ridx = s ? rB : rA;
            u32 hp[4][4][2];
            #pragma unroll
            for (int ct = 0; ct < 4; ++ct)
                #pragma unroll
                for (int g = 0; g < 4; ++g) {
                    float v0 = silu(acc[s][ct][4*g + 0]);
                    float v1 = silu(acc[s][ct][4*g + 1]);
                    float v2 = silu(acc[s][ct][4*g + 2]);
                    float v3 = silu(acc[s][ct][4*g + 3]);
                    hp[ct][g][0] = pack2(v0, v1);
                    hp[ct][g][1] = pack2(v2, v3);
                }

            f32x16 acc2[4];
            #pragma unroll
            for (int ct = 0; ct < 4; ++ct) acc2[ct] = (f32x16)0.0f;

            #pragma unroll
            for (int kb2 = 0; kb2 < 8; ++kb2) {
                const int om = 2 * kb2 + q;
                const int op = 2 * kb2 + 1 - q;
                u32 sv0 = hp[op >> 2][op & 3][0];
                u32 sv1 = hp[op >> 2][op & 3][1];
                u32 r0 = (u32)__shfl((int)sv0, lane ^ 32);
                u32 r1 = (u32)__shfl((int)sv1, lane ^ 32);
                u32 w0 = hp[om >> 2][om & 3][0];
                u32 w1v = hp[om >> 2][om & 3][1];
                Frag bf;
                if (q == 0) bf.u = (u32x4){w0, w1v, r0, r1};
                else        bf.u = (u32x4){r0, r1, w0, w1v};
                #pragma unroll
                for (int ct2 = 0; ct2 < 4; ++ct2) {
                    Frag a; a.u = *(const u32x4*)&wsl2[((size_t)(ct2 * 9 + kb2) * 64 + lane) * 4];
                    acc2[ct2] = mfma(a.b, bf.b, acc2[ct2]);
                }
            }
            {
                Frag bf; bf.u = (u32x4){0,0,0,0};
                if (q == 0) bf.u.x = 0x00003F80u;
                #pragma unroll
                for (int ct2 = 0; ct2 < 4; ++ct2) {
                    Frag a; a.u = *(const u32x4*)&wsl2[((size_t)(ct2 * 9 + 8) * 64 + lane) * 4];
                    acc2[ct2] = mfma(a.b, bf.b, acc2[ct2]);
                }
            }
            float* arow = aggr + (size_t)ridx * H;
            #pragma unroll
            for (int ct2 = 0; ct2 < 4; ++ct2)
                #pragma unroll
                for (int r = 0; r < 16; ++r) {
                    int m = ct2 * 32 + (r & 3) + 8 * (r >> 2) + 4 * q;
                    atomicAdd(arow + m, silu(acc2[ct2][r]));
                }
        }
    }
}

// ---------------------------------------------------------------------------
// Node update MLP: update = silu([x, aggr] @ uw1 + ub1) @ uw2 + ub2
// buf == d_out: aggr rows on entry, overwritten with the final update.
// ---------------------------------------------------------------------------
__global__ __launch_bounds__(256, 2) void node_mfma(
    const float* __restrict__ x, float* __restrict__ buf,
    const u32* __restrict__ ws, int N, int nIter)
{
    __shared__ u32 lds[16384];
    const u32* wsl1 = ws + 26624;
    const u32* wsl2 = ws + 44032;
    {
        const u32x4* src = (const u32x4*)wsl1;
        u32x4* dst = (u32x4*)lds;
        for (int i = threadIdx.x; i < 4096; i += 256) {
            int ln = i & 63, fb = i >> 6, ct = fb >> 4, kb = fb & 15;
            dst[i] = src[(ct * 17 + kb) * 64 + ln];
        }
    }
    __syncthreads();

    const int lane = threadIdx.x & 63;
    const int q = lane >> 5, el = lane & 31;
    const int gw  = blockIdx.x * 4 + (threadIdx.x >> 6);
    const int gws = gridDim.x * 4;

    for (int it = gw; it < nIter; it += gws) {
        const int n0 = it * 64;
        const int nA = n0 + el, nB = n0 + 32 + el;
        const int ncA = (nA < N) ? nA : (N - 1);
        const int ncB = (nB < N) ? nB : (N - 1);
        const float* xA = x + (size_t)ncA * H;  const float* gA = buf + (size_t)ncA * H;
        const float* xB = x + (size_t)ncB * H;  const float* gB = buf + (size_t)ncB * H;

        f32x16 acc[2][4];
        #pragma unroll
        for (int s = 0; s < 2; ++s)
            #pragma unroll
            for (int ct = 0; ct < 4; ++ct) acc[s][ct] = (f32x16)0.0f;

        #pragma unroll
        for (int kb = 0; kb < 16; ++kb) {
            const int f = kb * 16 + q * 8;
            const float* pA = (f < H) ? (xA + f) : (gA + f - H);
            const float* pB = (f < H) ? (xB + f) : (gB + f - H);
            bf16x8 bA = f8frag(*(const float4*)pA, *(const float4*)(pA + 4));
            bf16x8 bB = f8frag(*(const float4*)pB, *(const float4*)(pB + 4));
            #pragma unroll
            for (int ct = 0; ct < 4; ++ct) {
                Frag a; a.u = *(const u32x4*)&lds[((ct * 16 + kb) * 64 + lane) * 4];
                acc[0][ct] = mfma(a.b, bA, acc[0][ct]);
                acc[1][ct] = mfma(a.b, bB, acc[1][ct]);
            }
        }
        {
            Frag bp; bp.u = (u32x4){0,0,0,0};
            if (q == 0) bp.u.x = 0x00003F80u;
            #pragma unroll
            for (int ct = 0; ct < 4; ++ct) {
                Frag a; a.u = *(const u32x4*)&wsl1[((size_t)(ct * 17 + 16) * 64 + lane) * 4];
                acc[0][ct] = mfma(a.b, bp.b, acc[0][ct]);
                acc[1][ct] = mfma(a.b, bp.b, acc[1][ct]);
            }
        }

        #pragma unroll
        for (int s = 0; s < 2; ++s) {
            const int nn = s ? nB : nA;
            u32 hp[4][4][2];
            #pragma unroll
            for (int ct = 0; ct < 4; ++ct)
                #pragma unroll
                for (int g = 0; g < 4; ++g) {
                    float v0 = silu(acc[s][ct][4*g + 0]);
                    float v1 = silu(acc[s][ct][4*g + 1]);
                    float v2 = silu(acc[s][ct][4*g + 2]);
                    float v3 = silu(acc[s][ct][4*g + 3]);
                    hp[ct][g][0] = pack2(v0, v1);
                    hp[ct][g][1] = pack2(v2, v3);
                }

            f32x16 acc2[4];
            #pragma unroll
            for (int ct = 0; ct < 4; ++ct) acc2[ct] = (f32x16)0.0f;

            #pragma unroll
            for (int kb2 = 0; kb2 < 8; ++kb2) {
                const int om = 2 * kb2 + q;
                const int op = 2 * kb2 + 1 - q;
                u32 sv0 = hp[op >> 2][op & 3][0];
                u32 sv1 = hp[op >> 2][op & 3][1];
                u32 r0 = (u32)__shfl((int)sv0, lane ^ 32);
                u32 r1 = (u32)__shfl((int)sv1, lane ^ 32);
                u32 w0 = hp[om >> 2][om & 3][0];
                u32 w1v = hp[om >> 2][om & 3][1];
                Frag bf;
                if (q == 0) bf.u = (u32x4){w0, w1v, r0, r1};
                else        bf.u = (u32x4){r0, r1, w0, w1v};
                #pragma unroll
                for (int ct2 = 0; ct2 < 4; ++ct2) {
                    Frag a; a.u = *(const u32x4*)&wsl2[((size_t)(ct2 * 9 + kb2) * 64 + lane) * 4];
                    acc2[ct2] = mfma(a.b, bf.b, acc2[ct2]);
                }
            }
            {
                Frag bf; bf.u = (u32x4){0,0,0,0};
                if (q == 0) bf.u.x = 0x00003F80u;
                #pragma unroll
                for (int ct2 = 0; ct2 < 4; ++ct2) {
                    Frag a; a.u = *(const u32x4*)&wsl2[((size_t)(ct2 * 9 + 8) * 64 + lane) * 4];
                    acc2[ct2] = mfma(a.b, bf.b, acc2[ct2]);
                }
            }
            if (nn < N) {
                float* orow = buf + (size_t)nn * H;
                #pragma unroll
                for (int ct2 = 0; ct2 < 4; ++ct2)
                    #pragma unroll
                    for (int g = 0; g < 4; ++g) {
                        float4 v = { acc2[ct2][4*g + 0], acc2[ct2][4*g + 1],
                                     acc2[ct2][4*g + 2], acc2[ct2][4*g + 3] };
                        *(float4*)(orow + ct2 * 32 + 8 * g + 4 * q) = v;
                    }
            }
        }
    }
}

extern "C" void kernel_launch(void* const* d_in, const int* in_sizes, int n_in,
                              void* d_out, int out_size, void* d_ws, size_t ws_size,
                              hipStream_t stream) {
    const float* x    = (const float*)d_in[0];
    const float* pos  = (const float*)d_in[1];
    const int*   ei   = (const int*)d_in[2];
    const float* mw1  = (const float*)d_in[3];
    const float* mb1  = (const float*)d_in[4];
    const float* mw2  = (const float*)d_in[5];
    const float* mb2  = (const float*)d_in[6];
    const float* uw1  = (const float*)d_in[7];
    const float* ub1  = (const float*)d_in[8];
    const float* uw2  = (const float*)d_in[9];
    const float* ub2  = (const float*)d_in[10];

    const int N = in_sizes[0] / H;
    const int E = in_sizes[2] / 2;

    // ws layout (u32 units)
    const size_t FRAGS = 53248;                  // swizzled weight frags
    const size_t PO = FRAGS;                     // P: N*64 u32 (packed bf16 rows)
    const size_t QO = PO + (size_t)N * 64;       // Q: N*H fp32
    const size_t DG = QO + (size_t)N * H;        // deg: N int
    const size_t BK = DG + (size_t)N;            // bucket: N*64 int2
    const size_t ENDu = BK + (size_t)N * 128;
    const size_t need_bytes = ENDu * 4;

    u32* ws = (u32*)d_ws;
    prep_kernel<<<52, 256, 0, stream>>>(mw1, mb1, mw2, mb2, uw1, ub1, uw2, ub2, ws);

    float* buf = (float*)d_out;
    const int nIterN = (N + 63) / 64;

    if (ws_size >= need_bytes) {
        // ---- gather path: no fp32 atomics ----
        u32*   Pb   = ws + PO;
        float* Qb   = (float*)(ws + QO);
        int*   deg  = (int*)(ws + DG);
        int2*  bkt  = (int2*)(ws + BK);

        pq_gemm<<<196, 256, 0, stream>>>(x, ws, Pb, 0, 0, 1, N, nIterN);
        pq_gemm<<<196, 256, 0, stream>>>(x, ws, Qb, 8, 1, 0, N, nIterN);

        hipMemsetAsync(deg, 0, (size_t)N * sizeof(int), stream);
        bucket_fill<<<(E + 255) / 256, 256, 0, stream>>>(pos, ei, deg, bkt, E);

        aggregate_kernel<<<1024, 256, 0, stream>>>(Pb, Qb, mw1 + 256 * H, ws + 17408,
                                                   deg, bkt, buf, N);
        node_mfma<<<256, 256, 0, stream>>>(x, buf, ws, N, nIterN);
    } else {
        // ---- fallback: round-3 atomic scatter path ----
        hipMemsetAsync(buf, 0, (size_t)N * H * sizeof(float), stream);
        edge_mfma<<<512, 256, 0, stream>>>(x, pos, ei, ws, buf, E, E / 64);
        node_mfma<<<256, 256, 0, stream>>>(x, buf, ws, N, nIterN);
    }
}